// Round 8
// baseline (377.018 us; speedup 1.0000x reference)
//
#include <hip/hip_runtime.h>
#include <math.h>

#define BG   128            // graphs
#define NPER 1024           // nodes per graph, level 0
#define HDIM 128            // hidden
#define NEDGE (BG * NPER * 8)
#define NMAX (BG * NPER)    // 131072
#define EPG  (NEDGE / BG)   // 8192 edges per graph (contiguous slice!)
#define CAP  48             // per-node edge capacity (Poisson(8) tail ~1e-15)
#define PRE  16             // packed-meta entries per node (P(deg>16) ~ 0.4%)
#define CROWS 64            // conv tile rows

typedef __attribute__((ext_vector_type(8))) short s16x8;   // 8 bf16 (4 VGPRs)
typedef __attribute__((ext_vector_type(4))) float f32x4;   // MFMA C/D

static __device__ __forceinline__ ushort f2bf(float f) {   // RNE f32 -> bf16
  uint u = __float_as_uint(f);
  return (ushort)((u + 0x7fffu + ((u >> 16) & 1u)) >> 16);
}
static __device__ __forceinline__ float bf2f(ushort h) {
  return __uint_as_float(((uint)h) << 16);
}

// ---------------------------------------------------------------------------
// L0 merged count+fill: ONE atomic per edge gives both the slot position and
// (at the end) the degree. meta holds ONLY graph-local src ids.
// ---------------------------------------------------------------------------

__global__ __launch_bounds__(256) void countfill_kernel(
    const int* __restrict__ cr, const int* __restrict__ cc,
    int* __restrict__ cnt, int* __restrict__ meta8,
    int* __restrict__ srcext, int mask) {
  int e = blockIdx.x * 256 + threadIdx.x;
  int c = cc[e];
  int rl = cr[e] & mask;                       // graph-local row index
  int pos = atomicAdd(&cnt[c], 1);
  if (pos < PRE) {
    meta8[(size_t)c * PRE + pos] = rl;
  } else if (pos < CAP) {
    srcext[(size_t)c * CAP + pos] = rl;
  }
}

extern __shared__ float ldsbuf[];

// ---------------------------------------------------------------------------
// LDS-resident aggregation R8 = R7 + software-pipelined id prefetch (only
// change). R7's residual: each dst-iteration began with 4 int4 meta loads +
// deg whose L2/L3 latency (~600 cy) serialized ahead of the ds_reads; at 1
// block/CU TLP can't hide it. Now iteration n+1's ids/deg issue BEFORE
// iteration n's LDS phase (latency hides under 17 ds_reads + adds), and
// iteration 0's ids issue before __syncthreads (drain under the barrier).
// The `more` branch is block-uniform (npg % 128 == 0).
// ---------------------------------------------------------------------------

__global__ __launch_bounds__(1024) void agg_lds_kernel(
    const float* __restrict__ x, float* __restrict__ z,
    const int* __restrict__ meta8, const int* __restrict__ srcext,
    const int* __restrict__ deg, int npg) {
  float* sX = ldsbuf;                          // [npg][32], pre-scaled
  float* sDinv = sX + npg * 32;                // [npg]
  int g = blockIdx.x >> 2;
  int chunk = blockIdx.x & 3;
  int t = threadIdx.x;
  int base = g * npg;

  const float4* x4 = (const float4*)x;
  float4* sX4 = (float4*)sX;
  for (int i = t; i < npg * 8; i += 1024) {
    int r = i >> 3, l8 = i & 7;
    float dv = rsqrtf((float)deg[base + r] + 1.0f);
    float4 v = x4[(size_t)(base + r) * 32 + chunk * 8 + l8];
    v.x *= dv; v.y *= dv; v.z *= dv; v.w *= dv;
    sX4[i] = v;
  }
  for (int i = t; i < npg; i += 1024)
    sDinv[i] = rsqrtf((float)deg[base + i] + 1.0f);

  int dl = t >> 3, l = t & 7;                  // dst-local slot, lane 0..7
  const int4* m4 = (const int4*)meta8;
  float4* z4 = (float4*)z;

  // iteration-0 ids issue BEFORE the barrier: latency drains under it
  int4 c0 = m4[(size_t)(base + dl) * 4 + 0];
  int4 c1 = m4[(size_t)(base + dl) * 4 + 1];
  int4 c2 = m4[(size_t)(base + dl) * 4 + 2];
  int4 c3 = m4[(size_t)(base + dl) * 4 + 3];
  int cdg = deg[base + dl];

  __syncthreads();

  for (int dst = dl; dst < npg; dst += 128) {
    int nxt = dst + 128;
    bool more = nxt < npg;                     // block-uniform
    int4 n0 = c0, n1 = c1, n2 = c2, n3 = c3;
    int ndg = cdg;
    if (more) {                                // prefetch iter n+1 (vmcnt
      n0 = m4[(size_t)(base + nxt) * 4 + 0];   //  hides under LDS phase)
      n1 = m4[(size_t)(base + nxt) * 4 + 1];
      n2 = m4[(size_t)(base + nxt) * 4 + 2];
      n3 = m4[(size_t)(base + nxt) * 4 + 3];
      ndg = deg[base + nxt];
    }

    int node = base + dst;
    int d = cdg > CAP ? CAP : cdg;
    int dp = d > PRE ? PRE : d;
    float dc = sDinv[dst];

    // ---- cluster A: self + edges 0..7, 9 independent ds_read_b128 ----
    int sA0 = (0 < dp) ? c0.x : dst;           // invalid -> own row (valid
    int sA1 = (1 < dp) ? c0.y : dst;           //  ids are in-range: no mask)
    int sA2 = (2 < dp) ? c0.z : dst;
    int sA3 = (3 < dp) ? c0.w : dst;
    int sA4 = (4 < dp) ? c1.x : dst;
    int sA5 = (5 < dp) ? c1.y : dst;
    int sA6 = (6 < dp) ? c1.z : dst;
    int sA7 = (7 < dp) ? c1.w : dst;
    float4 w  = sX4[dst * 8 + l];              // self row (kept for corr)
    float4 p0 = sX4[sA0 * 8 + l];
    float4 p1 = sX4[sA1 * 8 + l];
    float4 p2 = sX4[sA2 * 8 + l];
    float4 p3 = sX4[sA3 * 8 + l];
    float4 p4 = sX4[sA4 * 8 + l];
    float4 p5 = sX4[sA5 * 8 + l];
    float4 p6 = sX4[sA6 * 8 + l];
    float4 p7 = sX4[sA7 * 8 + l];
    float4 a0, a1, a2, a3;
    a0.x = w.x + p0.x; a0.y = w.y + p0.y; a0.z = w.z + p0.z; a0.w = w.w + p0.w;
    a1.x = p1.x + p5.x; a1.y = p1.y + p5.y; a1.z = p1.z + p5.z; a1.w = p1.w + p5.w;
    a2.x = p2.x + p6.x; a2.y = p2.y + p6.y; a2.z = p2.z + p6.z; a2.w = p2.w + p6.w;
    a3.x = p3.x + p7.x; a3.y = p3.y + p7.y; a3.z = p3.z + p7.z; a3.w = p3.w + p7.w;
    a0.x += p4.x; a0.y += p4.y; a0.z += p4.z; a0.w += p4.w;

    // ---- cluster B: edges 8..15, 8 independent ds_read_b128 ----
    int sB0 = (8 < dp) ? c2.x : dst;
    int sB1 = (9 < dp) ? c2.y : dst;
    int sB2 = (10 < dp) ? c2.z : dst;
    int sB3 = (11 < dp) ? c2.w : dst;
    int sB4 = (12 < dp) ? c3.x : dst;
    int sB5 = (13 < dp) ? c3.y : dst;
    int sB6 = (14 < dp) ? c3.z : dst;
    int sB7 = (15 < dp) ? c3.w : dst;
    float4 q0 = sX4[sB0 * 8 + l];
    float4 q1 = sX4[sB1 * 8 + l];
    float4 q2 = sX4[sB2 * 8 + l];
    float4 q3 = sX4[sB3 * 8 + l];
    float4 q4 = sX4[sB4 * 8 + l];
    float4 q5 = sX4[sB5 * 8 + l];
    float4 q6 = sX4[sB6 * 8 + l];
    float4 q7 = sX4[sB7 * 8 + l];
    a0.x += q0.x; a0.y += q0.y; a0.z += q0.z; a0.w += q0.w;
    a1.x += q1.x; a1.y += q1.y; a1.z += q1.z; a1.w += q1.w;
    a2.x += q2.x; a2.y += q2.y; a2.z += q2.z; a2.w += q2.w;
    a3.x += q3.x; a3.y += q3.y; a3.z += q3.z; a3.w += q3.w;
    a0.x += q4.x; a0.y += q4.y; a0.z += q4.z; a0.w += q4.w;
    a1.x += q5.x; a1.y += q5.y; a1.z += q5.z; a1.w += q5.w;
    a2.x += q6.x; a2.y += q6.y; a2.z += q6.z; a2.w += q6.w;
    a3.x += q7.x; a3.y += q7.y; a3.z += q7.z; a3.w += q7.w;

    if (d > PRE) {                             // rare overflow (deg > 16)
      for (int e2 = PRE; e2 < d; ++e2) {
        int rl = srcext[(size_t)node * CAP + e2];
        float4 v0 = sX4[rl * 8 + l];
        a0.x += v0.x; a0.y += v0.y; a0.z += v0.z; a0.w += v0.w;
      }
    }

    float corr = (float)(PRE - dp);            // over-counted self reads
    float4 o;
    o.x = (a0.x + a1.x + a2.x + a3.x - corr * w.x) * dc;
    o.y = (a0.y + a1.y + a2.y + a3.y - corr * w.y) * dc;
    o.z = (a0.z + a1.z + a2.z + a3.z - corr * w.z) * dc;
    o.w = (a0.w + a1.w + a2.w + a3.w - corr * w.w) * dc;
    z4[(size_t)node * 32 + chunk * 8 + l] = o;

    c0 = n0; c1 = n1; c2 = n2; c3 = n3; cdg = ndg;
  }
}

// ---------------------------------------------------------------------------
// W prep: 3-way bf16 split (hi/mid/lo, residual <= 2^-27 rel) of each level's
// W, packed directly in MFMA B-fragment order for 16x16x32_bf16:
//   B[k][n]: lane l holds k = kt*32 + (l>>4)*8 + i, n = nt*16 + (l&15)
//   layout: [L][split][kt][nt][lane][i]  (each fragment = 16 B contiguous)
// Runs once; 3*3*32 KB total.
// ---------------------------------------------------------------------------

__global__ __launch_bounds__(256) void wsplit_kernel(
    const float* __restrict__ W0, const float* __restrict__ W1,
    const float* __restrict__ W2, ushort* __restrict__ wpk) {
  int id = blockIdx.x * 256 + threadIdx.x;     // 3*16384 total
  int L = id >> 14;
  int r = id & 16383;                          // ((kt*8+nt)*64+lane)*8+i
  int i = r & 7;
  int lane = (r >> 3) & 63;
  int nt = (r >> 9) & 7;
  int kt = (r >> 12) & 3;
  int k = kt * 32 + (lane >> 4) * 8 + i;
  int n = nt * 16 + (lane & 15);
  const float* W = (L == 0) ? W0 : (L == 1) ? W1 : W2;
  float v = W[k * HDIM + n];
  ushort h = f2bf(v);
  float r1 = v - bf2f(h);
  ushort m = f2bf(r1);
  ushort lo = f2bf(r1 - bf2f(m));
  size_t base = (size_t)L * 3 * 16384 + (size_t)r;
  wpk[base] = h;
  wpk[base + 16384] = m;
  wpk[base + 32768] = lo;
}

// ---------------------------------------------------------------------------
// conv via MFMA split-precision: h = relu(z @ W + b) in-place; score = h . p.
// Each wave owns 16 rows (4 waves = 64 rows/block). fp32 z is 3-way bf16
// split in registers; 6 product terms (hh,hm,mh,hl,lh,mm) per K-tile keep
// error ~2^-27 rel (fp32-rounding level -> topk ordering preserved).
// B-fragments: coalesced 16 B/lane dwordx4 from pre-packed wpk (L2-hot).
// No LDS, no barriers. 192 MFMAs/wave; dispatch is memory-bound on z/h.
// ---------------------------------------------------------------------------

__global__ __launch_bounds__(256) void conv_mfma_kernel(
    float* __restrict__ zh, const ushort* __restrict__ wpk,
    const float* __restrict__ bias, const float* __restrict__ p,
    float* __restrict__ score) {
  int t = threadIdx.x;
  int wv = t >> 6, l = t & 63;
  int lr = l & 15, lq = l >> 4;                // A-row in tile, quarter
  int arow = blockIdx.x * CROWS + wv * 16 + lr;
  const float* zrow = zh + (size_t)arow * HDIM + lq * 8;

  // ---- load + 3-way split A fragments (k = kt*32 + lq*8 + i) ----
  s16x8 ah[4], am[4], al[4];
  #pragma unroll
  for (int kt = 0; kt < 4; ++kt) {
    float4 v0 = ((const float4*)(zrow + kt * 32))[0];
    float4 v1 = ((const float4*)(zrow + kt * 32))[1];
    float f[8] = {v0.x, v0.y, v0.z, v0.w, v1.x, v1.y, v1.z, v1.w};
    #pragma unroll
    for (int i = 0; i < 8; ++i) {
      ushort h = f2bf(f[i]);
      float r1 = f[i] - bf2f(h);
      ushort m = f2bf(r1);
      ushort lo = f2bf(r1 - bf2f(m));
      ah[kt][i] = (short)h; am[kt][i] = (short)m; al[kt][i] = (short)lo;
    }
  }

  f32x4 acc[8];
  #pragma unroll
  for (int nt = 0; nt < 8; ++nt) acc[nt] = (f32x4)(0.f);

  const s16x8* wh = (const s16x8*)wpk;         // fragment-granular views
  const s16x8* wm = wh + 2048;
  const s16x8* wl = wm + 2048;

  #pragma unroll
  for (int kt = 0; kt < 4; ++kt) {
    #pragma unroll
    for (int nt = 0; nt < 8; ++nt) {
      int fi = (kt * 8 + nt) * 64 + l;
      s16x8 bh = wh[fi];
      s16x8 bm = wm[fi];
      s16x8 bl = wl[fi];
      acc[nt] = __builtin_amdgcn_mfma_f32_16x16x32_bf16(ah[kt], bh, acc[nt], 0, 0, 0);
      acc[nt] = __builtin_amdgcn_mfma_f32_16x16x32_bf16(ah[kt], bm, acc[nt], 0, 0, 0);
      acc[nt] = __builtin_amdgcn_mfma_f32_16x16x32_bf16(am[kt], bh, acc[nt], 0, 0, 0);
      acc[nt] = __builtin_amdgcn_mfma_f32_16x16x32_bf16(ah[kt], bl, acc[nt], 0, 0, 0);
      acc[nt] = __builtin_amdgcn_mfma_f32_16x16x32_bf16(al[kt], bh, acc[nt], 0, 0, 0);
      acc[nt] = __builtin_amdgcn_mfma_f32_16x16x32_bf16(am[kt], bm, acc[nt], 0, 0, 0);
    }
  }

  // ---- epilogue: bias + relu + score + in-place store ----
  // C/D layout (m89-verified): row = lq*4 + j, col = nt*16 + lr
  int orow = blockIdx.x * CROWS + wv * 16 + lq * 4;
  float part[4] = {0.f, 0.f, 0.f, 0.f};
  #pragma unroll
  for (int nt = 0; nt < 8; ++nt) {
    float bv = bias[nt * 16 + lr];
    float pv = p[nt * 16 + lr];
    #pragma unroll
    for (int j = 0; j < 4; ++j) {
      float hv = fmaxf(acc[nt][j] + bv, 0.f);
      part[j] += hv * pv;
      zh[(size_t)(orow + j) * HDIM + nt * 16 + lr] = hv;
    }
  }
  #pragma unroll
  for (int j = 0; j < 4; ++j) {
    #pragma unroll
    for (int s = 1; s < 16; s <<= 1) part[j] += __shfl_xor(part[j], s);
    if (lr == 0) score[orow + j] = part[j];
  }
}

// ---------------------------------------------------------------------------
// MEGA: per-graph block (P threads) — sort + pool/readout + relabel + next-
// layer count/fill via LDS. Coefficient-free meta: relabel loop writes meta8
// directly with ONE LDS atomic (slot+count combined); no second fill pass,
// no barrier between count and fill. L==2 also emits the final output.
// ---------------------------------------------------------------------------

__global__ __launch_bounds__(1024) void topk_mega_kernel(
    const float* __restrict__ score, const float* __restrict__ p,
    const float* __restrict__ h, float* __restrict__ xo,
    const int* __restrict__ in_r, const int* __restrict__ in_c,
    int* __restrict__ out_r, int* __restrict__ out_c,
    int* __restrict__ meta8, int* __restrict__ srcext,
    int* __restrict__ cnt, float* __restrict__ acc,
    float* __restrict__ outf, int P, int K, int L) {
  __shared__ float sv[1024];
  __shared__ int si[1024];
  __shared__ int snew[1024];
  __shared__ int scnt[512];
  __shared__ float s_pn;
  __shared__ float4 smx[32][32], ssm[32][32];
  int g = blockIdx.x;
  int t = threadIdx.x;

  if (L < 2 && t < 512) scnt[t] = 0;
  snew[t] = -1;
  if (t < 128) { float v = p[t]; sv[t] = v * v; }
  __syncthreads();
  for (int off = 64; off; off >>= 1) {
    if (t < off) sv[t] += sv[t + off];
    __syncthreads();
  }
  if (t == 0) s_pn = sqrtf(sv[0]);
  __syncthreads();
  float pn = s_pn;

  sv[t] = score[(size_t)g * P + t];
  si[t] = t;
  for (int size = 2; size <= P; size <<= 1) {
    for (int stride = size >> 1; stride; stride >>= 1) {
      __syncthreads();
      int j = t ^ stride;
      if (j > t) {
        float a = sv[t], b = sv[j];
        int ia = si[t], ib = si[j];
        bool tFirst = (a > b) || (a == b && ia < ib);
        bool up = ((t & size) == 0);
        if (up ? !tFirst : tFirst) {
          sv[t] = b; sv[j] = a;
          si[t] = ib; si[j] = ia;
        }
      }
    }
  }
  __syncthreads();
  if (t < K) {
    snew[si[t]] = t;                           // graph-LOCAL new id
    sv[t] = tanhf(sv[t] / pn);                 // sv now holds the scale
  }
  __syncthreads();

  // ---- gather + readout: group = 32 lanes, 16 rows per group ----
  int lane = t & 31, grp = t >> 5;             // ngrp = P/32; K/ngrp == 16
  const float4* h4 = (const float4*)h;
  float4* xo4 = (float4*)xo;
  size_t hbase = (size_t)g * P * 32;
  float4 mx = make_float4(-INFINITY, -INFINITY, -INFINITY, -INFINITY);
  float4 sm = make_float4(0.f, 0.f, 0.f, 0.f);
  #pragma unroll
  for (int i = 0; i < 16; ++i) {
    int j = grp * 16 + i;
    float th = sv[j];
    float4 v = h4[hbase + (size_t)si[j] * 32 + lane];
    v.x *= th; v.y *= th; v.z *= th; v.w *= th;
    xo4[((size_t)g * K + j) * 32 + lane] = v;
    mx.x = fmaxf(mx.x, v.x); mx.y = fmaxf(mx.y, v.y);
    mx.z = fmaxf(mx.z, v.z); mx.w = fmaxf(mx.w, v.w);
    sm.x += v.x; sm.y += v.y; sm.z += v.z; sm.w += v.w;
  }
  smx[grp][lane] = mx;
  ssm[grp][lane] = sm;
  __syncthreads();
  int ngrp = P >> 5;
  if (grp == 0) {
    for (int s2 = 1; s2 < ngrp; ++s2) {
      float4 m2 = smx[s2][lane], s3 = ssm[s2][lane];
      mx.x = fmaxf(mx.x, m2.x); mx.y = fmaxf(mx.y, m2.y);
      mx.z = fmaxf(mx.z, m2.z); mx.w = fmaxf(mx.w, m2.w);
      sm.x += s3.x; sm.y += s3.y; sm.z += s3.z; sm.w += s3.w;
    }
    int c0 = lane * 4;
    if (L < 2) {
      float* amax = acc + (size_t)L * BG * 256 + (size_t)g * 256;
      float* asum = amax + 128;
      amax[c0 + 0] = mx.x; amax[c0 + 1] = mx.y;
      amax[c0 + 2] = mx.z; amax[c0 + 3] = mx.w;
      asum[c0 + 0] = sm.x; asum[c0 + 1] = sm.y;
      asum[c0 + 2] = sm.z; asum[c0 + 3] = sm.w;
    } else {                                   // stash own readout in sv
      sv[c0 + 0] = mx.x; sv[c0 + 1] = mx.y;
      sv[c0 + 2] = mx.z; sv[c0 + 3] = mx.w;
      sv[128 + c0 + 0] = sm.x; sv[128 + c0 + 1] = sm.y;
      sv[128 + c0 + 2] = sm.z; sv[128 + c0 + 3] = sm.w;
    }
  }

  if (L == 2) {                                // fold final combine in
    __syncthreads();
    float v;
    const float* a0 = acc + (size_t)g * 256;
    const float* a1 = acc + (size_t)BG * 256 + (size_t)g * 256;
    if (t < 128) {
      v = a0[t] + a1[t] + sv[t];
    } else {
      v = a0[t] * (1.f / 512.f) + a1[t] * (1.f / 256.f) + sv[t] * (1.f / 128.f);
    }
    outf[g * 256 + t] = v;
    return;
  }

  // ---- relabel + count + fill in ONE pass (single LDS atomic per edge) ----
  int ept = EPG / P;                           // 8 (P=1024) or 16 (P=512)
  int ebase = g * EPG;
  for (int i = 0; i < ept; ++i) {
    int e = ebase + i * P + t;                 // coalesced
    int r = in_r[e];
    int nr = -1, nc = -1;
    if (r >= 0) {
      nr = snew[r & (P - 1)];
      nc = snew[in_c[e] & (P - 1)];
    }
    bool ok = (nr >= 0) && (nc >= 0);
    out_r[e] = ok ? g * K + nr : -1;
    out_c[e] = ok ? g * K + nc : -1;
    if (ok) {
      int pos = atomicAdd(&scnt[nc], 1);
      size_t gnode = (size_t)g * K + nc;
      if (pos < PRE) {
        meta8[gnode * PRE + pos] = nr;
      } else if (pos < CAP) {
        srcext[gnode * CAP + pos] = nr;
      }
    }
  }
  __syncthreads();                             // scnt complete
  if (t < K) cnt[g * K + t] = scnt[t];         // deg for next agg (coalesced)
}

// ---------------------------------------------------------------------------
// launch
// ---------------------------------------------------------------------------

extern "C" void kernel_launch(void* const* d_in, const int* in_sizes, int n_in,
                              void* d_out, int out_size, void* d_ws, size_t ws_size,
                              hipStream_t stream) {
  const float* x0 = (const float*)d_in[0];
  const int* erow = (const int*)d_in[1];
  const int* ecol = (const int*)d_in[2];
  const float* Wm[3] = {(const float*)d_in[3], (const float*)d_in[6], (const float*)d_in[9]};
  const float* bm[3] = {(const float*)d_in[4], (const float*)d_in[7], (const float*)d_in[10]};
  const float* pm[3] = {(const float*)d_in[5], (const float*)d_in[8], (const float*)d_in[11]};

  char* w = (char*)d_ws;
  size_t off = 0;
  auto alloc = [&](size_t bytes) -> void* {
    void* ptr = w + off;
    off = (off + bytes + 255) & ~(size_t)255;
    return ptr;
  };
  int* cur_row = (int*)alloc((size_t)NEDGE * 4);
  int* cur_col = (int*)alloc((size_t)NEDGE * 4);
  int* meta8   = (int*)alloc((size_t)NMAX * PRE * 4);
  int* srcext  = (int*)alloc((size_t)NMAX * CAP * 4);
  int* cnt     = (int*)alloc((size_t)NMAX * 4);
  float* score = (float*)alloc((size_t)NMAX * 4);
  float* acc   = (float*)alloc((size_t)2 * BG * 256 * 4);
  float* zh    = (float*)alloc((size_t)NMAX * HDIM * 4);
  float* x1    = (float*)alloc((size_t)BG * 512 * HDIM * 4);
  float* x2    = (float*)alloc((size_t)BG * 256 * HDIM * 4);
  float* x3    = (float*)alloc((size_t)BG * 128 * HDIM * 4);
  ushort* wpk  = (ushort*)alloc((size_t)3 * 3 * 16384 * 2);  // packed W splits

  // allow >64 KB dynamic LDS for the agg kernel (L0 needs 132 KB)
  hipFuncSetAttribute((const void*)agg_lds_kernel,
                      hipFuncAttributeMaxDynamicSharedMemorySize, 152 * 1024);

  hipMemsetAsync(cnt, 0, (size_t)NMAX * 4, stream);
  countfill_kernel<<<NEDGE / 256, 256, 0, stream>>>(erow, ecol, cnt, meta8,
                                                    srcext, NPER - 1);
  wsplit_kernel<<<(3 * 16384) / 256, 256, 0, stream>>>(Wm[0], Wm[1], Wm[2], wpk);

  const float* xin = x0;
  float* xout[3] = {x1, x2, x3};
  int Ps[3] = {1024, 512, 256};

  for (int L = 0; L < 3; ++L) {
    int P = Ps[L];
    int K = P >> 1;
    int n = BG * P;
    const int* in_r = (L == 0) ? erow : cur_row;
    const int* in_c = (L == 0) ? ecol : cur_col;
    size_t ldsBytes = (size_t)(P * 33) * 4;    // 32-ch chunk + dinv

    agg_lds_kernel<<<BG * 4, 1024, ldsBytes, stream>>>(
        xin, zh, meta8, srcext, cnt, P);
    conv_mfma_kernel<<<n / CROWS, 256, 0, stream>>>(
        zh, wpk + (size_t)L * 3 * 16384, bm[L], pm[L], score);
    topk_mega_kernel<<<BG, P, 0, stream>>>(
        score, pm[L], zh, xout[L], in_r, in_c, cur_row, cur_col,
        meta8, srcext, cnt, acc, (float*)d_out, P, K, L);
    xin = xout[L];
  }
}

// Round 9
// 369.370 us; speedup vs baseline: 1.0207x; 1.0207x over previous
//
#include <hip/hip_runtime.h>
#include <math.h>

#define BG   128            // graphs
#define NPER 1024           // nodes per graph, level 0
#define HDIM 128            // hidden
#define NEDGE (BG * NPER * 8)
#define NMAX (BG * NPER)    // 131072
#define EPG  (NEDGE / BG)   // 8192 edges per graph (contiguous slice!)
#define CAP  48             // per-node edge capacity (Poisson(8) tail ~1e-15)
#define PRE  16             // packed-meta entries per node (P(deg>16) ~ 0.4%)

typedef __attribute__((ext_vector_type(8))) short s16x8;   // 8 bf16 (4 VGPRs)
typedef __attribute__((ext_vector_type(4))) float f32x4;   // MFMA C/D

static __device__ __forceinline__ ushort f2bf(float f) {   // RNE f32 -> bf16
  uint u = __float_as_uint(f);
  return (ushort)((u + 0x7fffu + ((u >> 16) & 1u)) >> 16);
}
static __device__ __forceinline__ float bf2f(ushort h) {
  return __uint_as_float(((uint)h) << 16);
}

// ---------------------------------------------------------------------------
// L0 merged count+fill: ONE atomic per edge gives both the slot position and
// (at the end) the degree. meta holds ONLY graph-local src ids.
// ---------------------------------------------------------------------------

__global__ __launch_bounds__(256) void countfill_kernel(
    const int* __restrict__ cr, const int* __restrict__ cc,
    int* __restrict__ cnt, int* __restrict__ meta8,
    int* __restrict__ srcext, int mask) {
  int e = blockIdx.x * 256 + threadIdx.x;
  int c = cc[e];
  int rl = cr[e] & mask;                       // graph-local row index
  int pos = atomicAdd(&cnt[c], 1);
  if (pos < PRE) {
    meta8[(size_t)c * PRE + pos] = rl;
  } else if (pos < CAP) {
    srcext[(size_t)c * CAP + pos] = rl;
  }
}

// ---------------------------------------------------------------------------
// Degree-bucket ordering for L0 (L1/L2 orders are built in topk_mega's tail):
// order[g][slot] = graph-local node id, lows (deg<=8) first; odeg = its deg.
// Gives agg wave-uniform low/high branches (random order would exec both).
// ---------------------------------------------------------------------------

__global__ __launch_bounds__(1024) void degorder_kernel(
    const int* __restrict__ cnt, int* __restrict__ order,
    int* __restrict__ odeg) {
  __shared__ int bb[2];
  int g = blockIdx.x, t = threadIdx.x;
  if (t < 2) bb[t] = 0;
  __syncthreads();
  int d = cnt[g * NPER + t];
  int bkt = d > 8 ? 1 : 0;
  int pos = atomicAdd(&bb[bkt], 1);
  __syncthreads();
  int slot = bkt ? bb[0] + pos : pos;
  order[g * NPER + slot] = t;
  odeg[g * NPER + slot] = d;
}

extern __shared__ float ldsbuf[];

// ---------------------------------------------------------------------------
// LDS-resident aggregation R9 = R8 + degree-ordered dsts (only agg change).
// dsts walk the bucket-sorted order[]: 59% of nodes (deg<=8) execute a
// 9-read cluster only; 41% the full 17. Branch is wave-uniform post-sort
// (boundary wave excepted). Avg LDS reads/node 17 -> 12.3; low iterations
// halve their lgkm chain. order/odeg/meta are 2-deep software-pipelined.
// ---------------------------------------------------------------------------

__global__ __launch_bounds__(1024) void agg_lds_kernel(
    const float* __restrict__ x, float* __restrict__ z,
    const int* __restrict__ meta8, const int* __restrict__ srcext,
    const int* __restrict__ deg, const int* __restrict__ order,
    const int* __restrict__ odeg, int npg) {
  float* sX = ldsbuf;                          // [npg][32], pre-scaled
  float* sDinv = sX + npg * 32;                // [npg]
  int g = blockIdx.x >> 2;
  int chunk = blockIdx.x & 3;
  int t = threadIdx.x;
  int base = g * npg;

  const float4* x4 = (const float4*)x;
  float4* sX4 = (float4*)sX;
  for (int i = t; i < npg * 8; i += 1024) {
    int r = i >> 3, l8 = i & 7;
    float dv = rsqrtf((float)deg[base + r] + 1.0f);
    float4 v = x4[(size_t)(base + r) * 32 + chunk * 8 + l8];
    v.x *= dv; v.y *= dv; v.z *= dv; v.w *= dv;
    sX4[i] = v;
  }
  for (int i = t; i < npg; i += 1024)
    sDinv[i] = rsqrtf((float)deg[base + i] + 1.0f);

  int dl = t >> 3, l = t & 7;                  // dst-local slot, lane 0..7
  const int4* m4 = (const int4*)meta8;
  float4* z4 = (float4*)z;

  // 2-deep pipeline: ord/odeg for slot, slot+128; meta for slot (pre-barrier)
  int ordc = order[base + dl];
  int dpc  = odeg[base + dl];
  int ordn = order[base + dl + 128];           // npg >= 256 always
  int dpn  = odeg[base + dl + 128];
  int4 c0 = m4[(size_t)(base + ordc) * 4 + 0];
  int4 c1 = m4[(size_t)(base + ordc) * 4 + 1];
  int4 c2 = {0, 0, 0, 0}, c3 = {0, 0, 0, 0};
  if (dpc > 8) {
    c2 = m4[(size_t)(base + ordc) * 4 + 2];
    c3 = m4[(size_t)(base + ordc) * 4 + 3];
  }

  __syncthreads();

  for (int slot = dl; slot < npg; slot += 128) {
    int ordn2 = ordn, dpn2 = dpn;
    if (slot + 256 < npg) {                    // prefetch order 2 ahead
      ordn2 = order[base + slot + 256];
      dpn2  = odeg[base + slot + 256];
    }
    int4 n0 = {0,0,0,0}, n1 = {0,0,0,0}, n2 = {0,0,0,0}, n3 = {0,0,0,0};
    if (slot + 128 < npg) {                    // prefetch meta 1 ahead
      n0 = m4[(size_t)(base + ordn) * 4 + 0];
      n1 = m4[(size_t)(base + ordn) * 4 + 1];
      if (dpn > 8) {
        n2 = m4[(size_t)(base + ordn) * 4 + 2];
        n3 = m4[(size_t)(base + ordn) * 4 + 3];
      }
    }

    int dst = ordc;
    int node = base + dst;
    int d = dpc > CAP ? CAP : dpc;
    int dp = d > PRE ? PRE : d;
    float dc = sDinv[dst];

    // ---- cluster A: self + edges 0..7, 9 independent ds_read_b128 ----
    int sA0 = (0 < dp) ? c0.x : dst;           // invalid -> own row
    int sA1 = (1 < dp) ? c0.y : dst;
    int sA2 = (2 < dp) ? c0.z : dst;
    int sA3 = (3 < dp) ? c0.w : dst;
    int sA4 = (4 < dp) ? c1.x : dst;
    int sA5 = (5 < dp) ? c1.y : dst;
    int sA6 = (6 < dp) ? c1.z : dst;
    int sA7 = (7 < dp) ? c1.w : dst;
    float4 w  = sX4[dst * 8 + l];              // self row (kept for corr)
    float4 p0 = sX4[sA0 * 8 + l];
    float4 p1 = sX4[sA1 * 8 + l];
    float4 p2 = sX4[sA2 * 8 + l];
    float4 p3 = sX4[sA3 * 8 + l];
    float4 p4 = sX4[sA4 * 8 + l];
    float4 p5 = sX4[sA5 * 8 + l];
    float4 p6 = sX4[sA6 * 8 + l];
    float4 p7 = sX4[sA7 * 8 + l];
    float4 a0, a1, a2, a3;
    a0.x = w.x + p0.x; a0.y = w.y + p0.y; a0.z = w.z + p0.z; a0.w = w.w + p0.w;
    a1.x = p1.x + p5.x; a1.y = p1.y + p5.y; a1.z = p1.z + p5.z; a1.w = p1.w + p5.w;
    a2.x = p2.x + p6.x; a2.y = p2.y + p6.y; a2.z = p2.z + p6.z; a2.w = p2.w + p6.w;
    a3.x = p3.x + p7.x; a3.y = p3.y + p7.y; a3.z = p3.z + p7.z; a3.w = p3.w + p7.w;
    a0.x += p4.x; a0.y += p4.y; a0.z += p4.z; a0.w += p4.w;

    int nslots = 8;
    if (dp > 8) {                              // wave-uniform after sort
      // ---- cluster B: edges 8..15, 8 independent ds_read_b128 ----
      int sB0 = (8 < dp)  ? c2.x : dst;
      int sB1 = (9 < dp)  ? c2.y : dst;
      int sB2 = (10 < dp) ? c2.z : dst;
      int sB3 = (11 < dp) ? c2.w : dst;
      int sB4 = (12 < dp) ? c3.x : dst;
      int sB5 = (13 < dp) ? c3.y : dst;
      int sB6 = (14 < dp) ? c3.z : dst;
      int sB7 = (15 < dp) ? c3.w : dst;
      float4 q0 = sX4[sB0 * 8 + l];
      float4 q1 = sX4[sB1 * 8 + l];
      float4 q2 = sX4[sB2 * 8 + l];
      float4 q3 = sX4[sB3 * 8 + l];
      float4 q4 = sX4[sB4 * 8 + l];
      float4 q5 = sX4[sB5 * 8 + l];
      float4 q6 = sX4[sB6 * 8 + l];
      float4 q7 = sX4[sB7 * 8 + l];
      a0.x += q0.x; a0.y += q0.y; a0.z += q0.z; a0.w += q0.w;
      a1.x += q1.x; a1.y += q1.y; a1.z += q1.z; a1.w += q1.w;
      a2.x += q2.x; a2.y += q2.y; a2.z += q2.z; a2.w += q2.w;
      a3.x += q3.x; a3.y += q3.y; a3.z += q3.z; a3.w += q3.w;
      a0.x += q4.x; a0.y += q4.y; a0.z += q4.z; a0.w += q4.w;
      a1.x += q5.x; a1.y += q5.y; a1.z += q5.z; a1.w += q5.w;
      a2.x += q6.x; a2.y += q6.y; a2.z += q6.z; a2.w += q6.w;
      a3.x += q7.x; a3.y += q7.y; a3.z += q7.z; a3.w += q7.w;
      nslots = 16;
    }

    if (d > PRE) {                             // rare overflow (deg > 16)
      for (int e2 = PRE; e2 < d; ++e2) {
        int rl = srcext[(size_t)node * CAP + e2];
        float4 v0 = sX4[rl * 8 + l];
        a0.x += v0.x; a0.y += v0.y; a0.z += v0.z; a0.w += v0.w;
      }
    }

    float corr = (float)(nslots - dp);         // over-counted self reads
    float4 o;
    o.x = (a0.x + a1.x + a2.x + a3.x - corr * w.x) * dc;
    o.y = (a0.y + a1.y + a2.y + a3.y - corr * w.y) * dc;
    o.z = (a0.z + a1.z + a2.z + a3.z - corr * w.z) * dc;
    o.w = (a0.w + a1.w + a2.w + a3.w - corr * w.w) * dc;
    z4[(size_t)node * 32 + chunk * 8 + l] = o;

    ordc = ordn; dpc = dpn; ordn = ordn2; dpn = dpn2;
    c0 = n0; c1 = n1; c2 = n2; c3 = n3;
  }
}

// ---------------------------------------------------------------------------
// W prep: 3-way bf16 split (hi/mid/lo, residual <= 2^-27 rel) of each level's
// W, packed directly in MFMA B-fragment order for 16x16x32_bf16:
//   B[k][n]: lane l holds k = kt*32 + (l>>4)*8 + i, n = nt*16 + (l&15)
//   layout: [L][split][kt][nt][lane][i]  (each fragment = 16 B contiguous)
// Runs once; 3*3*32 KB total.
// ---------------------------------------------------------------------------

__global__ __launch_bounds__(256) void wsplit_kernel(
    const float* __restrict__ W0, const float* __restrict__ W1,
    const float* __restrict__ W2, ushort* __restrict__ wpk) {
  int id = blockIdx.x * 256 + threadIdx.x;     // 3*16384 total
  int L = id >> 14;
  int r = id & 16383;                          // ((kt*8+nt)*64+lane)*8+i
  int i = r & 7;
  int lane = (r >> 3) & 63;
  int nt = (r >> 9) & 7;
  int kt = (r >> 12) & 3;
  int k = kt * 32 + (lane >> 4) * 8 + i;
  int n = nt * 16 + (lane & 15);
  const float* W = (L == 0) ? W0 : (L == 1) ? W1 : W2;
  float v = W[k * HDIM + n];
  ushort h = f2bf(v);
  float r1 = v - bf2f(h);
  ushort m = f2bf(r1);
  ushort lo = f2bf(r1 - bf2f(m));
  size_t base = (size_t)L * 3 * 16384 + (size_t)r;
  wpk[base] = h;
  wpk[base + 16384] = m;
  wpk[base + 32768] = lo;
}

// ---------------------------------------------------------------------------
// conv via MFMA split-precision, R9: 32 rows/wave (two 16-row tiles, 64
// apart) — halves the per-wave-amortized W-fragment L2 traffic (786->393 MB
// over the L0 dispatch), previously the dominant pipe (~23 us at 34.5 TB/s).
// 12 MFMAs per 3 B-fragment loads. ~195 VGPR; __launch_bounds__(256,2)
// allows up to 256 (no spill), 2 blocks/CU.
// ---------------------------------------------------------------------------

__global__ __launch_bounds__(256, 2) void conv_mfma_kernel(
    float* __restrict__ zh, const ushort* __restrict__ wpk,
    const float* __restrict__ bias, const float* __restrict__ p,
    float* __restrict__ score) {
  int t = threadIdx.x;
  int wv = t >> 6, l = t & 63;
  int lr = l & 15, lq = l >> 4;                // A-row in tile, quarter
  int arowA = blockIdx.x * 128 + wv * 16 + lr;
  int arowB = arowA + 64;
  const float* zrowA = zh + (size_t)arowA * HDIM + lq * 8;
  const float* zrowB = zh + (size_t)arowB * HDIM + lq * 8;

  // ---- load + 3-way split A fragments for both row-tiles ----
  s16x8 ahA[4], amA[4], alA[4], ahB[4], amB[4], alB[4];
  #pragma unroll
  for (int kt = 0; kt < 4; ++kt) {
    float4 v0 = ((const float4*)(zrowA + kt * 32))[0];
    float4 v1 = ((const float4*)(zrowA + kt * 32))[1];
    float fA[8] = {v0.x, v0.y, v0.z, v0.w, v1.x, v1.y, v1.z, v1.w};
    float4 u0 = ((const float4*)(zrowB + kt * 32))[0];
    float4 u1 = ((const float4*)(zrowB + kt * 32))[1];
    float fB[8] = {u0.x, u0.y, u0.z, u0.w, u1.x, u1.y, u1.z, u1.w};
    #pragma unroll
    for (int i = 0; i < 8; ++i) {
      ushort h = f2bf(fA[i]);
      float r1 = fA[i] - bf2f(h);
      ushort m = f2bf(r1);
      ushort lo = f2bf(r1 - bf2f(m));
      ahA[kt][i] = (short)h; amA[kt][i] = (short)m; alA[kt][i] = (short)lo;
      h = f2bf(fB[i]);
      r1 = fB[i] - bf2f(h);
      m = f2bf(r1);
      lo = f2bf(r1 - bf2f(m));
      ahB[kt][i] = (short)h; amB[kt][i] = (short)m; alB[kt][i] = (short)lo;
    }
  }

  f32x4 accA[8], accB[8];
  #pragma unroll
  for (int nt = 0; nt < 8; ++nt) { accA[nt] = (f32x4)(0.f); accB[nt] = (f32x4)(0.f); }

  const s16x8* wh = (const s16x8*)wpk;         // fragment-granular views
  const s16x8* wm = wh + 2048;
  const s16x8* wl = wm + 2048;

  #pragma unroll
  for (int kt = 0; kt < 4; ++kt) {
    #pragma unroll
    for (int nt = 0; nt < 8; ++nt) {
      int fi = (kt * 8 + nt) * 64 + l;
      s16x8 bh = wh[fi];
      s16x8 bm = wm[fi];
      s16x8 bl = wl[fi];
      accA[nt] = __builtin_amdgcn_mfma_f32_16x16x32_bf16(ahA[kt], bh, accA[nt], 0, 0, 0);
      accA[nt] = __builtin_amdgcn_mfma_f32_16x16x32_bf16(ahA[kt], bm, accA[nt], 0, 0, 0);
      accA[nt] = __builtin_amdgcn_mfma_f32_16x16x32_bf16(amA[kt], bh, accA[nt], 0, 0, 0);
      accA[nt] = __builtin_amdgcn_mfma_f32_16x16x32_bf16(ahA[kt], bl, accA[nt], 0, 0, 0);
      accA[nt] = __builtin_amdgcn_mfma_f32_16x16x32_bf16(alA[kt], bh, accA[nt], 0, 0, 0);
      accA[nt] = __builtin_amdgcn_mfma_f32_16x16x32_bf16(amA[kt], bm, accA[nt], 0, 0, 0);
      accB[nt] = __builtin_amdgcn_mfma_f32_16x16x32_bf16(ahB[kt], bh, accB[nt], 0, 0, 0);
      accB[nt] = __builtin_amdgcn_mfma_f32_16x16x32_bf16(ahB[kt], bm, accB[nt], 0, 0, 0);
      accB[nt] = __builtin_amdgcn_mfma_f32_16x16x32_bf16(amB[kt], bh, accB[nt], 0, 0, 0);
      accB[nt] = __builtin_amdgcn_mfma_f32_16x16x32_bf16(ahB[kt], bl, accB[nt], 0, 0, 0);
      accB[nt] = __builtin_amdgcn_mfma_f32_16x16x32_bf16(alB[kt], bh, accB[nt], 0, 0, 0);
      accB[nt] = __builtin_amdgcn_mfma_f32_16x16x32_bf16(amB[kt], bm, accB[nt], 0, 0, 0);
    }
  }

  // ---- epilogue: bias + relu + score + in-place store (both tiles) ----
  // C/D layout (m89-verified): row = lq*4 + j, col = nt*16 + lr
  int orowA = blockIdx.x * 128 + wv * 16 + lq * 4;
  int orowB = orowA + 64;
  float partA[4] = {0.f, 0.f, 0.f, 0.f};
  float partB[4] = {0.f, 0.f, 0.f, 0.f};
  #pragma unroll
  for (int nt = 0; nt < 8; ++nt) {
    float bv = bias[nt * 16 + lr];
    float pv = p[nt * 16 + lr];
    #pragma unroll
    for (int j = 0; j < 4; ++j) {
      float hA = fmaxf(accA[nt][j] + bv, 0.f);
      partA[j] += hA * pv;
      zh[(size_t)(orowA + j) * HDIM + nt * 16 + lr] = hA;
      float hB = fmaxf(accB[nt][j] + bv, 0.f);
      partB[j] += hB * pv;
      zh[(size_t)(orowB + j) * HDIM + nt * 16 + lr] = hB;
    }
  }
  #pragma unroll
  for (int j = 0; j < 4; ++j) {
    #pragma unroll
    for (int s = 1; s < 16; s <<= 1) {
      partA[j] += __shfl_xor(partA[j], s);
      partB[j] += __shfl_xor(partB[j], s);
    }
    if (lr == 0) {
      score[orowA + j] = partA[j];
      score[orowB + j] = partB[j];
    }
  }
}

// ---------------------------------------------------------------------------
// MEGA: per-graph block (P threads) — sort + pool/readout + relabel + next-
// layer count/fill via LDS. Tail (L<2) now also emits the degree-bucketed
// order/odeg for the NEXT level's agg (scnt is already in LDS — free ride).
// ---------------------------------------------------------------------------

__global__ __launch_bounds__(1024) void topk_mega_kernel(
    const float* __restrict__ score, const float* __restrict__ p,
    const float* __restrict__ h, float* __restrict__ xo,
    const int* __restrict__ in_r, const int* __restrict__ in_c,
    int* __restrict__ out_r, int* __restrict__ out_c,
    int* __restrict__ meta8, int* __restrict__ srcext,
    int* __restrict__ cnt, float* __restrict__ acc,
    int* __restrict__ order, int* __restrict__ odeg,
    float* __restrict__ outf, int P, int K, int L) {
  __shared__ float sv[1024];
  __shared__ int si[1024];
  __shared__ int snew[1024];
  __shared__ int scnt[512];
  __shared__ int bb[2];
  __shared__ float s_pn;
  __shared__ float4 smx[32][32], ssm[32][32];
  int g = blockIdx.x;
  int t = threadIdx.x;

  if (L < 2 && t < 512) scnt[t] = 0;
  if (t < 2) bb[t] = 0;
  snew[t] = -1;
  if (t < 128) { float v = p[t]; sv[t] = v * v; }
  __syncthreads();
  for (int off = 64; off; off >>= 1) {
    if (t < off) sv[t] += sv[t + off];
    __syncthreads();
  }
  if (t == 0) s_pn = sqrtf(sv[0]);
  __syncthreads();
  float pn = s_pn;

  sv[t] = score[(size_t)g * P + t];
  si[t] = t;
  for (int size = 2; size <= P; size <<= 1) {
    for (int stride = size >> 1; stride; stride >>= 1) {
      __syncthreads();
      int j = t ^ stride;
      if (j > t) {
        float a = sv[t], b = sv[j];
        int ia = si[t], ib = si[j];
        bool tFirst = (a > b) || (a == b && ia < ib);
        bool up = ((t & size) == 0);
        if (up ? !tFirst : tFirst) {
          sv[t] = b; sv[j] = a;
          si[t] = ib; si[j] = ia;
        }
      }
    }
  }
  __syncthreads();
  if (t < K) {
    snew[si[t]] = t;                           // graph-LOCAL new id
    sv[t] = tanhf(sv[t] / pn);                 // sv now holds the scale
  }
  __syncthreads();

  // ---- gather + readout: group = 32 lanes, 16 rows per group ----
  int lane = t & 31, grp = t >> 5;             // ngrp = P/32; K/ngrp == 16
  const float4* h4 = (const float4*)h;
  float4* xo4 = (float4*)xo;
  size_t hbase = (size_t)g * P * 32;
  float4 mx = make_float4(-INFINITY, -INFINITY, -INFINITY, -INFINITY);
  float4 sm = make_float4(0.f, 0.f, 0.f, 0.f);
  #pragma unroll
  for (int i = 0; i < 16; ++i) {
    int j = grp * 16 + i;
    float th = sv[j];
    float4 v = h4[hbase + (size_t)si[j] * 32 + lane];
    v.x *= th; v.y *= th; v.z *= th; v.w *= th;
    xo4[((size_t)g * K + j) * 32 + lane] = v;
    mx.x = fmaxf(mx.x, v.x); mx.y = fmaxf(mx.y, v.y);
    mx.z = fmaxf(mx.z, v.z); mx.w = fmaxf(mx.w, v.w);
    sm.x += v.x; sm.y += v.y; sm.z += v.z; sm.w += v.w;
  }
  smx[grp][lane] = mx;
  ssm[grp][lane] = sm;
  __syncthreads();
  int ngrp = P >> 5;
  if (grp == 0) {
    for (int s2 = 1; s2 < ngrp; ++s2) {
      float4 m2 = smx[s2][lane], s3 = ssm[s2][lane];
      mx.x = fmaxf(mx.x, m2.x); mx.y = fmaxf(mx.y, m2.y);
      mx.z = fmaxf(mx.z, m2.z); mx.w = fmaxf(mx.w, m2.w);
      sm.x += s3.x; sm.y += s3.y; sm.z += s3.z; sm.w += s3.w;
    }
    int c0 = lane * 4;
    if (L < 2) {
      float* amax = acc + (size_t)L * BG * 256 + (size_t)g * 256;
      float* asum = amax + 128;
      amax[c0 + 0] = mx.x; amax[c0 + 1] = mx.y;
      amax[c0 + 2] = mx.z; amax[c0 + 3] = mx.w;
      asum[c0 + 0] = sm.x; asum[c0 + 1] = sm.y;
      asum[c0 + 2] = sm.z; asum[c0 + 3] = sm.w;
    } else {                                   // stash own readout in sv
      sv[c0 + 0] = mx.x; sv[c0 + 1] = mx.y;
      sv[c0 + 2] = mx.z; sv[c0 + 3] = mx.w;
      sv[128 + c0 + 0] = sm.x; sv[128 + c0 + 1] = sm.y;
      sv[128 + c0 + 2] = sm.z; sv[128 + c0 + 3] = sm.w;
    }
  }

  if (L == 2) {                                // fold final combine in
    __syncthreads();
    float v;
    const float* a0 = acc + (size_t)g * 256;
    const float* a1 = acc + (size_t)BG * 256 + (size_t)g * 256;
    if (t < 128) {
      v = a0[t] + a1[t] + sv[t];
    } else {
      v = a0[t] * (1.f / 512.f) + a1[t] * (1.f / 256.f) + sv[t] * (1.f / 128.f);
    }
    outf[g * 256 + t] = v;
    return;
  }

  // ---- relabel + count + fill in ONE pass (single LDS atomic per edge) ----
  int ept = EPG / P;                           // 8 (P=1024) or 16 (P=512)
  int ebase = g * EPG;
  for (int i = 0; i < ept; ++i) {
    int e = ebase + i * P + t;                 // coalesced
    int r = in_r[e];
    int nr = -1, nc = -1;
    if (r >= 0) {
      nr = snew[r & (P - 1)];
      nc = snew[in_c[e] & (P - 1)];
    }
    bool ok = (nr >= 0) && (nc >= 0);
    out_r[e] = ok ? g * K + nr : -1;
    out_c[e] = ok ? g * K + nc : -1;
    if (ok) {
      int pos = atomicAdd(&scnt[nc], 1);
      size_t gnode = (size_t)g * K + nc;
      if (pos < PRE) {
        meta8[gnode * PRE + pos] = nr;
      } else if (pos < CAP) {
        srcext[gnode * CAP + pos] = nr;
      }
    }
  }
  __syncthreads();                             // scnt complete
  if (t < K) cnt[g * K + t] = scnt[t];         // deg for next agg (coalesced)

  // ---- degree-bucket order for next level's agg (lows first) ----
  int bkt = 0, bpos = 0, bdeg = 0;
  if (t < K) {
    bdeg = scnt[t];
    bkt = bdeg > 8 ? 1 : 0;
    bpos = atomicAdd(&bb[bkt], 1);
  }
  __syncthreads();
  if (t < K) {
    int slot = bkt ? bb[0] + bpos : bpos;
    order[g * K + slot] = t;
    odeg[g * K + slot] = bdeg;
  }
}

// ---------------------------------------------------------------------------
// launch
// ---------------------------------------------------------------------------

extern "C" void kernel_launch(void* const* d_in, const int* in_sizes, int n_in,
                              void* d_out, int out_size, void* d_ws, size_t ws_size,
                              hipStream_t stream) {
  const float* x0 = (const float*)d_in[0];
  const int* erow = (const int*)d_in[1];
  const int* ecol = (const int*)d_in[2];
  const float* Wm[3] = {(const float*)d_in[3], (const float*)d_in[6], (const float*)d_in[9]};
  const float* bm[3] = {(const float*)d_in[4], (const float*)d_in[7], (const float*)d_in[10]};
  const float* pm[3] = {(const float*)d_in[5], (const float*)d_in[8], (const float*)d_in[11]};

  char* w = (char*)d_ws;
  size_t off = 0;
  auto alloc = [&](size_t bytes) -> void* {
    void* ptr = w + off;
    off = (off + bytes + 255) & ~(size_t)255;
    return ptr;
  };
  int* cur_row = (int*)alloc((size_t)NEDGE * 4);
  int* cur_col = (int*)alloc((size_t)NEDGE * 4);
  int* meta8   = (int*)alloc((size_t)NMAX * PRE * 4);
  int* srcext  = (int*)alloc((size_t)NMAX * CAP * 4);
  int* cnt     = (int*)alloc((size_t)NMAX * 4);
  int* order   = (int*)alloc((size_t)NMAX * 4);
  int* odeg    = (int*)alloc((size_t)NMAX * 4);
  float* score = (float*)alloc((size_t)NMAX * 4);
  float* acc   = (float*)alloc((size_t)2 * BG * 256 * 4);
  float* zh    = (float*)alloc((size_t)NMAX * HDIM * 4);
  float* x1    = (float*)alloc((size_t)BG * 512 * HDIM * 4);
  float* x2    = (float*)alloc((size_t)BG * 256 * HDIM * 4);
  float* x3    = (float*)alloc((size_t)BG * 128 * HDIM * 4);
  ushort* wpk  = (ushort*)alloc((size_t)3 * 3 * 16384 * 2);  // packed W splits

  // allow >64 KB dynamic LDS for the agg kernel (L0 needs 132 KB)
  hipFuncSetAttribute((const void*)agg_lds_kernel,
                      hipFuncAttributeMaxDynamicSharedMemorySize, 152 * 1024);

  hipMemsetAsync(cnt, 0, (size_t)NMAX * 4, stream);
  countfill_kernel<<<NEDGE / 256, 256, 0, stream>>>(erow, ecol, cnt, meta8,
                                                    srcext, NPER - 1);
  wsplit_kernel<<<(3 * 16384) / 256, 256, 0, stream>>>(Wm[0], Wm[1], Wm[2], wpk);
  degorder_kernel<<<BG, 1024, 0, stream>>>(cnt, order, odeg);

  const float* xin = x0;
  float* xout[3] = {x1, x2, x3};
  int Ps[3] = {1024, 512, 256};

  for (int L = 0; L < 3; ++L) {
    int P = Ps[L];
    int K = P >> 1;
    int n = BG * P;
    const int* in_r = (L == 0) ? erow : cur_row;
    const int* in_c = (L == 0) ? ecol : cur_col;
    size_t ldsBytes = (size_t)(P * 33) * 4;    // 32-ch chunk + dinv

    agg_lds_kernel<<<BG * 4, 1024, ldsBytes, stream>>>(
        xin, zh, meta8, srcext, cnt, order, odeg, P);
    conv_mfma_kernel<<<n / 128, 256, 0, stream>>>(
        zh, wpk + (size_t)L * 3 * 16384, bm[L], pm[L], score);
    topk_mega_kernel<<<BG, P, 0, stream>>>(
        score, pm[L], zh, xout[L], in_r, in_c, cur_row, cur_col,
        meta8, srcext, cnt, acc, order, odeg, (float*)d_out, P, K, L);
    xin = xout[L];
  }
}

// Round 10
// 327.126 us; speedup vs baseline: 1.1525x; 1.1291x over previous
//
#include <hip/hip_runtime.h>
#include <math.h>

#define BG   128            // graphs
#define NPER 1024           // nodes per graph, level 0
#define HDIM 128            // hidden
#define NEDGE (BG * NPER * 8)
#define NMAX (BG * NPER)    // 131072
#define EPG  (NEDGE / BG)   // 8192 edges per graph (contiguous slice!)
#define CAP  48             // per-node edge capacity (Poisson(8) tail ~1e-15)
#define PRE  16             // packed-meta entries per node (P(deg>16) ~ 0.4%)

typedef __attribute__((ext_vector_type(8))) short s16x8;   // 8 bf16 (4 VGPRs)
typedef __attribute__((ext_vector_type(4))) float f32x4;   // MFMA C/D

static __device__ __forceinline__ ushort f2bf(float f) {   // RNE f32 -> bf16
  uint u = __float_as_uint(f);
  return (ushort)((u + 0x7fffu + ((u >> 16) & 1u)) >> 16);
}
static __device__ __forceinline__ float bf2f(ushort h) {
  return __uint_as_float(((uint)h) << 16);
}

extern __shared__ float ldsbuf[];

// ---------------------------------------------------------------------------
// R10: countfill rebuilt as graph-local LDS kernel. Old version: 1M threads,
// each one global atomicAdd (random, ~600cy, must return) + dependent
// scattered 4B global write -> 51 us at 0.6% VALU. New: block = graph;
// meta (64KB) + cnt (4KB) live in LDS; edges read coalesced int4; LDS
// atomic + LDS scatter; one coalesced int4 flush. Also folds the degree-
// bucket ordering (scnt already in LDS) and kills the cnt memset.
// ---------------------------------------------------------------------------

__global__ __launch_bounds__(1024) void countfill_lds_kernel(
    const int* __restrict__ cr, const int* __restrict__ cc,
    int* __restrict__ cnt, int* __restrict__ meta8,
    int* __restrict__ srcext, int* __restrict__ order,
    int* __restrict__ odeg) {
  int* smeta = (int*)ldsbuf;                   // [NPER][PRE]
  int* scnt  = smeta + NPER * PRE;             // [NPER]
  int* sbb   = scnt + NPER;                    // [2]
  int g = blockIdx.x, t = threadIdx.x;
  scnt[t] = 0;
  if (t < 2) sbb[t] = 0;
  __syncthreads();

  const int4* cr4 = (const int4*)(cr + (size_t)g * EPG);
  const int4* cc4 = (const int4*)(cc + (size_t)g * EPG);
  #pragma unroll
  for (int i = 0; i < 2; ++i) {                // 8 edges: 2x int4 per array
    int4 r = cr4[t * 2 + i];
    int4 c = cc4[t * 2 + i];
    int rl, cl, pos;
    cl = c.x & (NPER - 1); rl = r.x & (NPER - 1);
    pos = atomicAdd(&scnt[cl], 1);
    if (pos < PRE) smeta[cl * PRE + pos] = rl;
    else if (pos < CAP) srcext[((size_t)g * NPER + cl) * CAP + pos] = rl;
    cl = c.y & (NPER - 1); rl = r.y & (NPER - 1);
    pos = atomicAdd(&scnt[cl], 1);
    if (pos < PRE) smeta[cl * PRE + pos] = rl;
    else if (pos < CAP) srcext[((size_t)g * NPER + cl) * CAP + pos] = rl;
    cl = c.z & (NPER - 1); rl = r.z & (NPER - 1);
    pos = atomicAdd(&scnt[cl], 1);
    if (pos < PRE) smeta[cl * PRE + pos] = rl;
    else if (pos < CAP) srcext[((size_t)g * NPER + cl) * CAP + pos] = rl;
    cl = c.w & (NPER - 1); rl = r.w & (NPER - 1);
    pos = atomicAdd(&scnt[cl], 1);
    if (pos < PRE) smeta[cl * PRE + pos] = rl;
    else if (pos < CAP) srcext[((size_t)g * NPER + cl) * CAP + pos] = rl;
  }
  __syncthreads();

  // ---- coalesced flush: meta (64 KB) + cnt ----
  int4* mo = (int4*)(meta8 + (size_t)g * NPER * PRE);
  const int4* sm4 = (const int4*)smeta;
  #pragma unroll
  for (int i = 0; i < 4; ++i) mo[i * 1024 + t] = sm4[i * 1024 + t];
  int d = scnt[t];
  cnt[g * NPER + t] = d;

  // ---- degree-bucket order (lows first) — replaces degorder_kernel ----
  int bkt = d > 8 ? 1 : 0;
  int bpos = atomicAdd(&sbb[bkt], 1);
  __syncthreads();
  int slot = bkt ? sbb[0] + bpos : bpos;
  order[g * NPER + slot] = t;
  odeg[g * NPER + slot] = d;
}

// ---------------------------------------------------------------------------
// LDS-resident aggregation (R9 structure, unchanged): degree-ordered dsts,
// named-register read clusters, 2-deep order/meta software pipeline.
// ---------------------------------------------------------------------------

__global__ __launch_bounds__(1024) void agg_lds_kernel(
    const float* __restrict__ x, float* __restrict__ z,
    const int* __restrict__ meta8, const int* __restrict__ srcext,
    const int* __restrict__ deg, const int* __restrict__ order,
    const int* __restrict__ odeg, int npg) {
  float* sX = ldsbuf;                          // [npg][32], pre-scaled
  float* sDinv = sX + npg * 32;                // [npg]
  int g = blockIdx.x >> 2;
  int chunk = blockIdx.x & 3;
  int t = threadIdx.x;
  int base = g * npg;

  const float4* x4 = (const float4*)x;
  float4* sX4 = (float4*)sX;
  for (int i = t; i < npg * 8; i += 1024) {
    int r = i >> 3, l8 = i & 7;
    float dv = rsqrtf((float)deg[base + r] + 1.0f);
    float4 v = x4[(size_t)(base + r) * 32 + chunk * 8 + l8];
    v.x *= dv; v.y *= dv; v.z *= dv; v.w *= dv;
    sX4[i] = v;
  }
  for (int i = t; i < npg; i += 1024)
    sDinv[i] = rsqrtf((float)deg[base + i] + 1.0f);

  int dl = t >> 3, l = t & 7;                  // dst-local slot, lane 0..7
  const int4* m4 = (const int4*)meta8;
  float4* z4 = (float4*)z;

  // 2-deep pipeline: ord/odeg for slot, slot+128; meta for slot (pre-barrier)
  int ordc = order[base + dl];
  int dpc  = odeg[base + dl];
  int ordn = order[base + dl + 128];           // npg >= 256 always
  int dpn  = odeg[base + dl + 128];
  int4 c0 = m4[(size_t)(base + ordc) * 4 + 0];
  int4 c1 = m4[(size_t)(base + ordc) * 4 + 1];
  int4 c2 = {0, 0, 0, 0}, c3 = {0, 0, 0, 0};
  if (dpc > 8) {
    c2 = m4[(size_t)(base + ordc) * 4 + 2];
    c3 = m4[(size_t)(base + ordc) * 4 + 3];
  }

  __syncthreads();

  for (int slot = dl; slot < npg; slot += 128) {
    int ordn2 = ordn, dpn2 = dpn;
    if (slot + 256 < npg) {                    // prefetch order 2 ahead
      ordn2 = order[base + slot + 256];
      dpn2  = odeg[base + slot + 256];
    }
    int4 n0 = {0,0,0,0}, n1 = {0,0,0,0}, n2 = {0,0,0,0}, n3 = {0,0,0,0};
    if (slot + 128 < npg) {                    // prefetch meta 1 ahead
      n0 = m4[(size_t)(base + ordn) * 4 + 0];
      n1 = m4[(size_t)(base + ordn) * 4 + 1];
      if (dpn > 8) {
        n2 = m4[(size_t)(base + ordn) * 4 + 2];
        n3 = m4[(size_t)(base + ordn) * 4 + 3];
      }
    }

    int dst = ordc;
    int node = base + dst;
    int d = dpc > CAP ? CAP : dpc;
    int dp = d > PRE ? PRE : d;
    float dc = sDinv[dst];

    // ---- cluster A: self + edges 0..7, 9 independent ds_read_b128 ----
    int sA0 = (0 < dp) ? c0.x : dst;           // invalid -> own row
    int sA1 = (1 < dp) ? c0.y : dst;
    int sA2 = (2 < dp) ? c0.z : dst;
    int sA3 = (3 < dp) ? c0.w : dst;
    int sA4 = (4 < dp) ? c1.x : dst;
    int sA5 = (5 < dp) ? c1.y : dst;
    int sA6 = (6 < dp) ? c1.z : dst;
    int sA7 = (7 < dp) ? c1.w : dst;
    float4 w  = sX4[dst * 8 + l];              // self row (kept for corr)
    float4 p0 = sX4[sA0 * 8 + l];
    float4 p1 = sX4[sA1 * 8 + l];
    float4 p2 = sX4[sA2 * 8 + l];
    float4 p3 = sX4[sA3 * 8 + l];
    float4 p4 = sX4[sA4 * 8 + l];
    float4 p5 = sX4[sA5 * 8 + l];
    float4 p6 = sX4[sA6 * 8 + l];
    float4 p7 = sX4[sA7 * 8 + l];
    float4 a0, a1, a2, a3;
    a0.x = w.x + p0.x; a0.y = w.y + p0.y; a0.z = w.z + p0.z; a0.w = w.w + p0.w;
    a1.x = p1.x + p5.x; a1.y = p1.y + p5.y; a1.z = p1.z + p5.z; a1.w = p1.w + p5.w;
    a2.x = p2.x + p6.x; a2.y = p2.y + p6.y; a2.z = p2.z + p6.z; a2.w = p2.w + p6.w;
    a3.x = p3.x + p7.x; a3.y = p3.y + p7.y; a3.z = p3.z + p7.z; a3.w = p3.w + p7.w;
    a0.x += p4.x; a0.y += p4.y; a0.z += p4.z; a0.w += p4.w;

    int nslots = 8;
    if (dp > 8) {                              // wave-uniform after sort
      // ---- cluster B: edges 8..15, 8 independent ds_read_b128 ----
      int sB0 = (8 < dp)  ? c2.x : dst;
      int sB1 = (9 < dp)  ? c2.y : dst;
      int sB2 = (10 < dp) ? c2.z : dst;
      int sB3 = (11 < dp) ? c2.w : dst;
      int sB4 = (12 < dp) ? c3.x : dst;
      int sB5 = (13 < dp) ? c3.y : dst;
      int sB6 = (14 < dp) ? c3.z : dst;
      int sB7 = (15 < dp) ? c3.w : dst;
      float4 q0 = sX4[sB0 * 8 + l];
      float4 q1 = sX4[sB1 * 8 + l];
      float4 q2 = sX4[sB2 * 8 + l];
      float4 q3 = sX4[sB3 * 8 + l];
      float4 q4 = sX4[sB4 * 8 + l];
      float4 q5 = sX4[sB5 * 8 + l];
      float4 q6 = sX4[sB6 * 8 + l];
      float4 q7 = sX4[sB7 * 8 + l];
      a0.x += q0.x; a0.y += q0.y; a0.z += q0.z; a0.w += q0.w;
      a1.x += q1.x; a1.y += q1.y; a1.z += q1.z; a1.w += q1.w;
      a2.x += q2.x; a2.y += q2.y; a2.z += q2.z; a2.w += q2.w;
      a3.x += q3.x; a3.y += q3.y; a3.z += q3.z; a3.w += q3.w;
      a0.x += q4.x; a0.y += q4.y; a0.z += q4.z; a0.w += q4.w;
      a1.x += q5.x; a1.y += q5.y; a1.z += q5.z; a1.w += q5.w;
      a2.x += q6.x; a2.y += q6.y; a2.z += q6.z; a2.w += q6.w;
      a3.x += q7.x; a3.y += q7.y; a3.z += q7.z; a3.w += q7.w;
      nslots = 16;
    }

    if (d > PRE) {                             // rare overflow (deg > 16)
      for (int e2 = PRE; e2 < d; ++e2) {
        int rl = srcext[(size_t)node * CAP + e2];
        float4 v0 = sX4[rl * 8 + l];
        a0.x += v0.x; a0.y += v0.y; a0.z += v0.z; a0.w += v0.w;
      }
    }

    float corr = (float)(nslots - dp);         // over-counted self reads
    float4 o;
    o.x = (a0.x + a1.x + a2.x + a3.x - corr * w.x) * dc;
    o.y = (a0.y + a1.y + a2.y + a3.y - corr * w.y) * dc;
    o.z = (a0.z + a1.z + a2.z + a3.z - corr * w.z) * dc;
    o.w = (a0.w + a1.w + a2.w + a3.w - corr * w.w) * dc;
    z4[(size_t)node * 32 + chunk * 8 + l] = o;

    ordc = ordn; dpc = dpn; ordn = ordn2; dpn = dpn2;
    c0 = n0; c1 = n1; c2 = n2; c3 = n3;
  }
}

// ---------------------------------------------------------------------------
// W prep: 3-way bf16 split (hi/mid/lo, residual <= 2^-27 rel) of each level's
// W, packed directly in MFMA B-fragment order for 16x16x32_bf16.
// ---------------------------------------------------------------------------

__global__ __launch_bounds__(256) void wsplit_kernel(
    const float* __restrict__ W0, const float* __restrict__ W1,
    const float* __restrict__ W2, ushort* __restrict__ wpk) {
  int id = blockIdx.x * 256 + threadIdx.x;     // 3*16384 total
  int L = id >> 14;
  int r = id & 16383;                          // ((kt*8+nt)*64+lane)*8+i
  int i = r & 7;
  int lane = (r >> 3) & 63;
  int nt = (r >> 9) & 7;
  int kt = (r >> 12) & 3;
  int k = kt * 32 + (lane >> 4) * 8 + i;
  int n = nt * 16 + (lane & 15);
  const float* W = (L == 0) ? W0 : (L == 1) ? W1 : W2;
  float v = W[k * HDIM + n];
  ushort h = f2bf(v);
  float r1 = v - bf2f(h);
  ushort m = f2bf(r1);
  ushort lo = f2bf(r1 - bf2f(m));
  size_t base = (size_t)L * 3 * 16384 + (size_t)r;
  wpk[base] = h;
  wpk[base + 16384] = m;
  wpk[base + 32768] = lo;
}

// ---------------------------------------------------------------------------
// conv via MFMA split-precision, 32 rows/wave (R9 structure, unchanged).
// ---------------------------------------------------------------------------

__global__ __launch_bounds__(256, 2) void conv_mfma_kernel(
    float* __restrict__ zh, const ushort* __restrict__ wpk,
    const float* __restrict__ bias, const float* __restrict__ p,
    float* __restrict__ score) {
  int t = threadIdx.x;
  int wv = t >> 6, l = t & 63;
  int lr = l & 15, lq = l >> 4;                // A-row in tile, quarter
  int arowA = blockIdx.x * 128 + wv * 16 + lr;
  int arowB = arowA + 64;
  const float* zrowA = zh + (size_t)arowA * HDIM + lq * 8;
  const float* zrowB = zh + (size_t)arowB * HDIM + lq * 8;

  // ---- load + 3-way split A fragments for both row-tiles ----
  s16x8 ahA[4], amA[4], alA[4], ahB[4], amB[4], alB[4];
  #pragma unroll
  for (int kt = 0; kt < 4; ++kt) {
    float4 v0 = ((const float4*)(zrowA + kt * 32))[0];
    float4 v1 = ((const float4*)(zrowA + kt * 32))[1];
    float fA[8] = {v0.x, v0.y, v0.z, v0.w, v1.x, v1.y, v1.z, v1.w};
    float4 u0 = ((const float4*)(zrowB + kt * 32))[0];
    float4 u1 = ((const float4*)(zrowB + kt * 32))[1];
    float fB[8] = {u0.x, u0.y, u0.z, u0.w, u1.x, u1.y, u1.z, u1.w};
    #pragma unroll
    for (int i = 0; i < 8; ++i) {
      ushort h = f2bf(fA[i]);
      float r1 = fA[i] - bf2f(h);
      ushort m = f2bf(r1);
      ushort lo = f2bf(r1 - bf2f(m));
      ahA[kt][i] = (short)h; amA[kt][i] = (short)m; alA[kt][i] = (short)lo;
      h = f2bf(fB[i]);
      r1 = fB[i] - bf2f(h);
      m = f2bf(r1);
      lo = f2bf(r1 - bf2f(m));
      ahB[kt][i] = (short)h; amB[kt][i] = (short)m; alB[kt][i] = (short)lo;
    }
  }

  f32x4 accA[8], accB[8];
  #pragma unroll
  for (int nt = 0; nt < 8; ++nt) { accA[nt] = (f32x4)(0.f); accB[nt] = (f32x4)(0.f); }

  const s16x8* wh = (const s16x8*)wpk;         // fragment-granular views
  const s16x8* wm = wh + 2048;
  const s16x8* wl = wm + 2048;

  #pragma unroll
  for (int kt = 0; kt < 4; ++kt) {
    #pragma unroll
    for (int nt = 0; nt < 8; ++nt) {
      int fi = (kt * 8 + nt) * 64 + l;
      s16x8 bh = wh[fi];
      s16x8 bm = wm[fi];
      s16x8 bl = wl[fi];
      accA[nt] = __builtin_amdgcn_mfma_f32_16x16x32_bf16(ahA[kt], bh, accA[nt], 0, 0, 0);
      accA[nt] = __builtin_amdgcn_mfma_f32_16x16x32_bf16(ahA[kt], bm, accA[nt], 0, 0, 0);
      accA[nt] = __builtin_amdgcn_mfma_f32_16x16x32_bf16(amA[kt], bh, accA[nt], 0, 0, 0);
      accA[nt] = __builtin_amdgcn_mfma_f32_16x16x32_bf16(ahA[kt], bl, accA[nt], 0, 0, 0);
      accA[nt] = __builtin_amdgcn_mfma_f32_16x16x32_bf16(alA[kt], bh, accA[nt], 0, 0, 0);
      accA[nt] = __builtin_amdgcn_mfma_f32_16x16x32_bf16(amA[kt], bm, accA[nt], 0, 0, 0);
      accB[nt] = __builtin_amdgcn_mfma_f32_16x16x32_bf16(ahB[kt], bh, accB[nt], 0, 0, 0);
      accB[nt] = __builtin_amdgcn_mfma_f32_16x16x32_bf16(ahB[kt], bm, accB[nt], 0, 0, 0);
      accB[nt] = __builtin_amdgcn_mfma_f32_16x16x32_bf16(amB[kt], bh, accB[nt], 0, 0, 0);
      accB[nt] = __builtin_amdgcn_mfma_f32_16x16x32_bf16(ahB[kt], bl, accB[nt], 0, 0, 0);
      accB[nt] = __builtin_amdgcn_mfma_f32_16x16x32_bf16(alB[kt], bh, accB[nt], 0, 0, 0);
      accB[nt] = __builtin_amdgcn_mfma_f32_16x16x32_bf16(amB[kt], bm, accB[nt], 0, 0, 0);
    }
  }

  // ---- epilogue: bias + relu + score + in-place store (both tiles) ----
  // C/D layout (m89-verified): row = lq*4 + j, col = nt*16 + lr
  int orowA = blockIdx.x * 128 + wv * 16 + lq * 4;
  int orowB = orowA + 64;
  float partA[4] = {0.f, 0.f, 0.f, 0.f};
  float partB[4] = {0.f, 0.f, 0.f, 0.f};
  #pragma unroll
  for (int nt = 0; nt < 8; ++nt) {
    float bv = bias[nt * 16 + lr];
    float pv = p[nt * 16 + lr];
    #pragma unroll
    for (int j = 0; j < 4; ++j) {
      float hA = fmaxf(accA[nt][j] + bv, 0.f);
      partA[j] += hA * pv;
      zh[(size_t)(orowA + j) * HDIM + nt * 16 + lr] = hA;
      float hB = fmaxf(accB[nt][j] + bv, 0.f);
      partB[j] += hB * pv;
      zh[(size_t)(orowB + j) * HDIM + nt * 16 + lr] = hB;
    }
  }
  #pragma unroll
  for (int j = 0; j < 4; ++j) {
    #pragma unroll
    for (int s = 1; s < 16; s <<= 1) {
      partA[j] += __shfl_xor(partA[j], s);
      partB[j] += __shfl_xor(partB[j], s);
    }
    if (lr == 0) {
      score[orowA + j] = partA[j];
      score[orowB + j] = partB[j];
    }
  }
}

// ---------------------------------------------------------------------------
// MEGA: per-graph block (P threads) — sort + pool/readout + relabel + next-
// layer count/fill via LDS. Tail (L<2) also emits the degree-bucketed
// order/odeg for the NEXT level's agg. (R9 structure, unchanged.)
// ---------------------------------------------------------------------------

__global__ __launch_bounds__(1024) void topk_mega_kernel(
    const float* __restrict__ score, const float* __restrict__ p,
    const float* __restrict__ h, float* __restrict__ xo,
    const int* __restrict__ in_r, const int* __restrict__ in_c,
    int* __restrict__ out_r, int* __restrict__ out_c,
    int* __restrict__ meta8, int* __restrict__ srcext,
    int* __restrict__ cnt, float* __restrict__ acc,
    int* __restrict__ order, int* __restrict__ odeg,
    float* __restrict__ outf, int P, int K, int L) {
  __shared__ float sv[1024];
  __shared__ int si[1024];
  __shared__ int snew[1024];
  __shared__ int scnt[512];
  __shared__ int bb[2];
  __shared__ float s_pn;
  __shared__ float4 smx[32][32], ssm[32][32];
  int g = blockIdx.x;
  int t = threadIdx.x;

  if (L < 2 && t < 512) scnt[t] = 0;
  if (t < 2) bb[t] = 0;
  snew[t] = -1;
  if (t < 128) { float v = p[t]; sv[t] = v * v; }
  __syncthreads();
  for (int off = 64; off; off >>= 1) {
    if (t < off) sv[t] += sv[t + off];
    __syncthreads();
  }
  if (t == 0) s_pn = sqrtf(sv[0]);
  __syncthreads();
  float pn = s_pn;

  sv[t] = score[(size_t)g * P + t];
  si[t] = t;
  for (int size = 2; size <= P; size <<= 1) {
    for (int stride = size >> 1; stride; stride >>= 1) {
      __syncthreads();
      int j = t ^ stride;
      if (j > t) {
        float a = sv[t], b = sv[j];
        int ia = si[t], ib = si[j];
        bool tFirst = (a > b) || (a == b && ia < ib);
        bool up = ((t & size) == 0);
        if (up ? !tFirst : tFirst) {
          sv[t] = b; sv[j] = a;
          si[t] = ib; si[j] = ia;
        }
      }
    }
  }
  __syncthreads();
  if (t < K) {
    snew[si[t]] = t;                           // graph-LOCAL new id
    sv[t] = tanhf(sv[t] / pn);                 // sv now holds the scale
  }
  __syncthreads();

  // ---- gather + readout: group = 32 lanes, 16 rows per group ----
  int lane = t & 31, grp = t >> 5;             // ngrp = P/32; K/ngrp == 16
  const float4* h4 = (const float4*)h;
  float4* xo4 = (float4*)xo;
  size_t hbase = (size_t)g * P * 32;
  float4 mx = make_float4(-INFINITY, -INFINITY, -INFINITY, -INFINITY);
  float4 sm = make_float4(0.f, 0.f, 0.f, 0.f);
  #pragma unroll
  for (int i = 0; i < 16; ++i) {
    int j = grp * 16 + i;
    float th = sv[j];
    float4 v = h4[hbase + (size_t)si[j] * 32 + lane];
    v.x *= th; v.y *= th; v.z *= th; v.w *= th;
    xo4[((size_t)g * K + j) * 32 + lane] = v;
    mx.x = fmaxf(mx.x, v.x); mx.y = fmaxf(mx.y, v.y);
    mx.z = fmaxf(mx.z, v.z); mx.w = fmaxf(mx.w, v.w);
    sm.x += v.x; sm.y += v.y; sm.z += v.z; sm.w += v.w;
  }
  smx[grp][lane] = mx;
  ssm[grp][lane] = sm;
  __syncthreads();
  int ngrp = P >> 5;
  if (grp == 0) {
    for (int s2 = 1; s2 < ngrp; ++s2) {
      float4 m2 = smx[s2][lane], s3 = ssm[s2][lane];
      mx.x = fmaxf(mx.x, m2.x); mx.y = fmaxf(mx.y, m2.y);
      mx.z = fmaxf(mx.z, m2.z); mx.w = fmaxf(mx.w, m2.w);
      sm.x += s3.x; sm.y += s3.y; sm.z += s3.z; sm.w += s3.w;
    }
    int c0 = lane * 4;
    if (L < 2) {
      float* amax = acc + (size_t)L * BG * 256 + (size_t)g * 256;
      float* asum = amax + 128;
      amax[c0 + 0] = mx.x; amax[c0 + 1] = mx.y;
      amax[c0 + 2] = mx.z; amax[c0 + 3] = mx.w;
      asum[c0 + 0] = sm.x; asum[c0 + 1] = sm.y;
      asum[c0 + 2] = sm.z; asum[c0 + 3] = sm.w;
    } else {                                   // stash own readout in sv
      sv[c0 + 0] = mx.x; sv[c0 + 1] = mx.y;
      sv[c0 + 2] = mx.z; sv[c0 + 3] = mx.w;
      sv[128 + c0 + 0] = sm.x; sv[128 + c0 + 1] = sm.y;
      sv[128 + c0 + 2] = sm.z; sv[128 + c0 + 3] = sm.w;
    }
  }

  if (L == 2) {                                // fold final combine in
    __syncthreads();
    float v;
    const float* a0 = acc + (size_t)g * 256;
    const float* a1 = acc + (size_t)BG * 256 + (size_t)g * 256;
    if (t < 128) {
      v = a0[t] + a1[t] + sv[t];
    } else {
      v = a0[t] * (1.f / 512.f) + a1[t] * (1.f / 256.f) + sv[t] * (1.f / 128.f);
    }
    outf[g * 256 + t] = v;
    return;
  }

  // ---- relabel + count + fill in ONE pass (single LDS atomic per edge) ----
  int ept = EPG / P;                           // 8 (P=1024) or 16 (P=512)
  int ebase = g * EPG;
  for (int i = 0; i < ept; ++i) {
    int e = ebase + i * P + t;                 // coalesced
    int r = in_r[e];
    int nr = -1, nc = -1;
    if (r >= 0) {
      nr = snew[r & (P - 1)];
      nc = snew[in_c[e] & (P - 1)];
    }
    bool ok = (nr >= 0) && (nc >= 0);
    out_r[e] = ok ? g * K + nr : -1;
    out_c[e] = ok ? g * K + nc : -1;
    if (ok) {
      int pos = atomicAdd(&scnt[nc], 1);
      size_t gnode = (size_t)g * K + nc;
      if (pos < PRE) {
        meta8[gnode * PRE + pos] = nr;
      } else if (pos < CAP) {
        srcext[gnode * CAP + pos] = nr;
      }
    }
  }
  __syncthreads();                             // scnt complete
  if (t < K) cnt[g * K + t] = scnt[t];         // deg for next agg (coalesced)

  // ---- degree-bucket order for next level's agg (lows first) ----
  int bkt = 0, bpos = 0, bdeg = 0;
  if (t < K) {
    bdeg = scnt[t];
    bkt = bdeg > 8 ? 1 : 0;
    bpos = atomicAdd(&bb[bkt], 1);
  }
  __syncthreads();
  if (t < K) {
    int slot = bkt ? bb[0] + bpos : bpos;
    order[g * K + slot] = t;
    odeg[g * K + slot] = bdeg;
  }
}

// ---------------------------------------------------------------------------
// launch
// ---------------------------------------------------------------------------

extern "C" void kernel_launch(void* const* d_in, const int* in_sizes, int n_in,
                              void* d_out, int out_size, void* d_ws, size_t ws_size,
                              hipStream_t stream) {
  const float* x0 = (const float*)d_in[0];
  const int* erow = (const int*)d_in[1];
  const int* ecol = (const int*)d_in[2];
  const float* Wm[3] = {(const float*)d_in[3], (const float*)d_in[6], (const float*)d_in[9]};
  const float* bm[3] = {(const float*)d_in[4], (const float*)d_in[7], (const float*)d_in[10]};
  const float* pm[3] = {(const float*)d_in[5], (const float*)d_in[8], (const float*)d_in[11]};

  char* w = (char*)d_ws;
  size_t off = 0;
  auto alloc = [&](size_t bytes) -> void* {
    void* ptr = w + off;
    off = (off + bytes + 255) & ~(size_t)255;
    return ptr;
  };
  int* cur_row = (int*)alloc((size_t)NEDGE * 4);
  int* cur_col = (int*)alloc((size_t)NEDGE * 4);
  int* meta8   = (int*)alloc((size_t)NMAX * PRE * 4);
  int* srcext  = (int*)alloc((size_t)NMAX * CAP * 4);
  int* cnt     = (int*)alloc((size_t)NMAX * 4);
  int* order   = (int*)alloc((size_t)NMAX * 4);
  int* odeg    = (int*)alloc((size_t)NMAX * 4);
  float* score = (float*)alloc((size_t)NMAX * 4);
  float* acc   = (float*)alloc((size_t)2 * BG * 256 * 4);
  float* zh    = (float*)alloc((size_t)NMAX * HDIM * 4);
  float* x1    = (float*)alloc((size_t)BG * 512 * HDIM * 4);
  float* x2    = (float*)alloc((size_t)BG * 256 * HDIM * 4);
  float* x3    = (float*)alloc((size_t)BG * 128 * HDIM * 4);
  ushort* wpk  = (ushort*)alloc((size_t)3 * 3 * 16384 * 2);  // packed W splits

  // allow >64 KB dynamic LDS (agg L0: 132 KB; countfill: 69.7 KB)
  hipFuncSetAttribute((const void*)agg_lds_kernel,
                      hipFuncAttributeMaxDynamicSharedMemorySize, 152 * 1024);
  hipFuncSetAttribute((const void*)countfill_lds_kernel,
                      hipFuncAttributeMaxDynamicSharedMemorySize, 72 * 1024);

  size_t cfLds = (size_t)(NPER * PRE + NPER + 2) * 4;
  countfill_lds_kernel<<<BG, 1024, cfLds, stream>>>(
      erow, ecol, cnt, meta8, srcext, order, odeg);
  wsplit_kernel<<<(3 * 16384) / 256, 256, 0, stream>>>(Wm[0], Wm[1], Wm[2], wpk);

  const float* xin = x0;
  float* xout[3] = {x1, x2, x3};
  int Ps[3] = {1024, 512, 256};

  for (int L = 0; L < 3; ++L) {
    int P = Ps[L];
    int K = P >> 1;
    int n = BG * P;
    const int* in_r = (L == 0) ? erow : cur_row;
    const int* in_c = (L == 0) ? ecol : cur_col;
    size_t ldsBytes = (size_t)(P * 33) * 4;    // 32-ch chunk + dinv

    agg_lds_kernel<<<BG * 4, 1024, ldsBytes, stream>>>(
        xin, zh, meta8, srcext, cnt, order, odeg, P);
    conv_mfma_kernel<<<n / 128, 256, 0, stream>>>(
        zh, wpk + (size_t)L * 3 * 16384, bm[L], pm[L], score);
    topk_mega_kernel<<<BG, P, 0, stream>>>(
        score, pm[L], zh, xout[L], in_r, in_c, cur_row, cur_col,
        meta8, srcext, cnt, acc, order, odeg, (float*)d_out, P, K, L);
    xin = xout[L];
  }
}

// Round 11
// 317.592 us; speedup vs baseline: 1.1871x; 1.0300x over previous
//
#include <hip/hip_runtime.h>
#include <math.h>

#define BG   128            // graphs
#define NPER 1024           // nodes per graph, level 0
#define HDIM 128            // hidden
#define NEDGE (BG * NPER * 8)
#define NMAX (BG * NPER)    // 131072
#define EPG  (NEDGE / BG)   // 8192 edges per graph (contiguous slice!)
#define CAP  48             // per-node edge capacity (Poisson(8) tail ~1e-15)
#define PRE  16             // packed-meta entries per node (P(deg>16) ~ 0.4%)

typedef __attribute__((ext_vector_type(8))) short s16x8;   // 8 bf16 (4 VGPRs)
typedef __attribute__((ext_vector_type(4))) float f32x4;   // MFMA C/D

static __device__ __forceinline__ ushort f2bf(float f) {   // RNE f32 -> bf16
  uint u = __float_as_uint(f);
  return (ushort)((u + 0x7fffu + ((u >> 16) & 1u)) >> 16);
}
static __device__ __forceinline__ float bf2f(ushort h) {
  return __uint_as_float(((uint)h) << 16);
}

extern __shared__ float ldsbuf[];

// ---------------------------------------------------------------------------
// countfill as graph-local LDS kernel (R10, unchanged): block = graph; meta
// (64KB) + cnt (4KB) in LDS; coalesced int4 edge reads; LDS atomic+scatter;
// coalesced flush; folds degree-bucket ordering; no cnt memset needed.
// ---------------------------------------------------------------------------

__global__ __launch_bounds__(1024) void countfill_lds_kernel(
    const int* __restrict__ cr, const int* __restrict__ cc,
    int* __restrict__ cnt, int* __restrict__ meta8,
    int* __restrict__ srcext, int* __restrict__ order,
    int* __restrict__ odeg) {
  int* smeta = (int*)ldsbuf;                   // [NPER][PRE]
  int* scnt  = smeta + NPER * PRE;             // [NPER]
  int* sbb   = scnt + NPER;                    // [2]
  int g = blockIdx.x, t = threadIdx.x;
  scnt[t] = 0;
  if (t < 2) sbb[t] = 0;
  __syncthreads();

  const int4* cr4 = (const int4*)(cr + (size_t)g * EPG);
  const int4* cc4 = (const int4*)(cc + (size_t)g * EPG);
  #pragma unroll
  for (int i = 0; i < 2; ++i) {                // 8 edges: 2x int4 per array
    int4 r = cr4[t * 2 + i];
    int4 c = cc4[t * 2 + i];
    int rl, cl, pos;
    cl = c.x & (NPER - 1); rl = r.x & (NPER - 1);
    pos = atomicAdd(&scnt[cl], 1);
    if (pos < PRE) smeta[cl * PRE + pos] = rl;
    else if (pos < CAP) srcext[((size_t)g * NPER + cl) * CAP + pos] = rl;
    cl = c.y & (NPER - 1); rl = r.y & (NPER - 1);
    pos = atomicAdd(&scnt[cl], 1);
    if (pos < PRE) smeta[cl * PRE + pos] = rl;
    else if (pos < CAP) srcext[((size_t)g * NPER + cl) * CAP + pos] = rl;
    cl = c.z & (NPER - 1); rl = r.z & (NPER - 1);
    pos = atomicAdd(&scnt[cl], 1);
    if (pos < PRE) smeta[cl * PRE + pos] = rl;
    else if (pos < CAP) srcext[((size_t)g * NPER + cl) * CAP + pos] = rl;
    cl = c.w & (NPER - 1); rl = r.w & (NPER - 1);
    pos = atomicAdd(&scnt[cl], 1);
    if (pos < PRE) smeta[cl * PRE + pos] = rl;
    else if (pos < CAP) srcext[((size_t)g * NPER + cl) * CAP + pos] = rl;
  }
  __syncthreads();

  // ---- coalesced flush: meta (64 KB) + cnt ----
  int4* mo = (int4*)(meta8 + (size_t)g * NPER * PRE);
  const int4* sm4 = (const int4*)smeta;
  #pragma unroll
  for (int i = 0; i < 4; ++i) mo[i * 1024 + t] = sm4[i * 1024 + t];
  int d = scnt[t];
  cnt[g * NPER + t] = d;

  // ---- degree-bucket order (lows first) ----
  int bkt = d > 8 ? 1 : 0;
  int bpos = atomicAdd(&sbb[bkt], 1);
  __syncthreads();
  int slot = bkt ? sbb[0] + bpos : bpos;
  order[g * NPER + slot] = t;
  odeg[g * NPER + slot] = d;
}

// ---------------------------------------------------------------------------
// LDS-resident aggregation (R9 structure, unchanged): degree-ordered dsts,
// named-register read clusters, 2-deep order/meta software pipeline.
// ---------------------------------------------------------------------------

__global__ __launch_bounds__(1024) void agg_lds_kernel(
    const float* __restrict__ x, float* __restrict__ z,
    const int* __restrict__ meta8, const int* __restrict__ srcext,
    const int* __restrict__ deg, const int* __restrict__ order,
    const int* __restrict__ odeg, int npg) {
  float* sX = ldsbuf;                          // [npg][32], pre-scaled
  float* sDinv = sX + npg * 32;                // [npg]
  int g = blockIdx.x >> 2;
  int chunk = blockIdx.x & 3;
  int t = threadIdx.x;
  int base = g * npg;

  const float4* x4 = (const float4*)x;
  float4* sX4 = (float4*)sX;
  for (int i = t; i < npg * 8; i += 1024) {
    int r = i >> 3, l8 = i & 7;
    float dv = rsqrtf((float)deg[base + r] + 1.0f);
    float4 v = x4[(size_t)(base + r) * 32 + chunk * 8 + l8];
    v.x *= dv; v.y *= dv; v.z *= dv; v.w *= dv;
    sX4[i] = v;
  }
  for (int i = t; i < npg; i += 1024)
    sDinv[i] = rsqrtf((float)deg[base + i] + 1.0f);

  int dl = t >> 3, l = t & 7;                  // dst-local slot, lane 0..7
  const int4* m4 = (const int4*)meta8;
  float4* z4 = (float4*)z;

  // 2-deep pipeline: ord/odeg for slot, slot+128; meta for slot (pre-barrier)
  int ordc = order[base + dl];
  int dpc  = odeg[base + dl];
  int ordn = order[base + dl + 128];           // npg >= 256 always
  int dpn  = odeg[base + dl + 128];
  int4 c0 = m4[(size_t)(base + ordc) * 4 + 0];
  int4 c1 = m4[(size_t)(base + ordc) * 4 + 1];
  int4 c2 = {0, 0, 0, 0}, c3 = {0, 0, 0, 0};
  if (dpc > 8) {
    c2 = m4[(size_t)(base + ordc) * 4 + 2];
    c3 = m4[(size_t)(base + ordc) * 4 + 3];
  }

  __syncthreads();

  for (int slot = dl; slot < npg; slot += 128) {
    int ordn2 = ordn, dpn2 = dpn;
    if (slot + 256 < npg) {                    // prefetch order 2 ahead
      ordn2 = order[base + slot + 256];
      dpn2  = odeg[base + slot + 256];
    }
    int4 n0 = {0,0,0,0}, n1 = {0,0,0,0}, n2 = {0,0,0,0}, n3 = {0,0,0,0};
    if (slot + 128 < npg) {                    // prefetch meta 1 ahead
      n0 = m4[(size_t)(base + ordn) * 4 + 0];
      n1 = m4[(size_t)(base + ordn) * 4 + 1];
      if (dpn > 8) {
        n2 = m4[(size_t)(base + ordn) * 4 + 2];
        n3 = m4[(size_t)(base + ordn) * 4 + 3];
      }
    }

    int dst = ordc;
    int node = base + dst;
    int d = dpc > CAP ? CAP : dpc;
    int dp = d > PRE ? PRE : d;
    float dc = sDinv[dst];

    // ---- cluster A: self + edges 0..7, 9 independent ds_read_b128 ----
    int sA0 = (0 < dp) ? c0.x : dst;           // invalid -> own row
    int sA1 = (1 < dp) ? c0.y : dst;
    int sA2 = (2 < dp) ? c0.z : dst;
    int sA3 = (3 < dp) ? c0.w : dst;
    int sA4 = (4 < dp) ? c1.x : dst;
    int sA5 = (5 < dp) ? c1.y : dst;
    int sA6 = (6 < dp) ? c1.z : dst;
    int sA7 = (7 < dp) ? c1.w : dst;
    float4 w  = sX4[dst * 8 + l];              // self row (kept for corr)
    float4 p0 = sX4[sA0 * 8 + l];
    float4 p1 = sX4[sA1 * 8 + l];
    float4 p2 = sX4[sA2 * 8 + l];
    float4 p3 = sX4[sA3 * 8 + l];
    float4 p4 = sX4[sA4 * 8 + l];
    float4 p5 = sX4[sA5 * 8 + l];
    float4 p6 = sX4[sA6 * 8 + l];
    float4 p7 = sX4[sA7 * 8 + l];
    float4 a0, a1, a2, a3;
    a0.x = w.x + p0.x; a0.y = w.y + p0.y; a0.z = w.z + p0.z; a0.w = w.w + p0.w;
    a1.x = p1.x + p5.x; a1.y = p1.y + p5.y; a1.z = p1.z + p5.z; a1.w = p1.w + p5.w;
    a2.x = p2.x + p6.x; a2.y = p2.y + p6.y; a2.z = p2.z + p6.z; a2.w = p2.w + p6.w;
    a3.x = p3.x + p7.x; a3.y = p3.y + p7.y; a3.z = p3.z + p7.z; a3.w = p3.w + p7.w;
    a0.x += p4.x; a0.y += p4.y; a0.z += p4.z; a0.w += p4.w;

    int nslots = 8;
    if (dp > 8) {                              // wave-uniform after sort
      // ---- cluster B: edges 8..15, 8 independent ds_read_b128 ----
      int sB0 = (8 < dp)  ? c2.x : dst;
      int sB1 = (9 < dp)  ? c2.y : dst;
      int sB2 = (10 < dp) ? c2.z : dst;
      int sB3 = (11 < dp) ? c2.w : dst;
      int sB4 = (12 < dp) ? c3.x : dst;
      int sB5 = (13 < dp) ? c3.y : dst;
      int sB6 = (14 < dp) ? c3.z : dst;
      int sB7 = (15 < dp) ? c3.w : dst;
      float4 q0 = sX4[sB0 * 8 + l];
      float4 q1 = sX4[sB1 * 8 + l];
      float4 q2 = sX4[sB2 * 8 + l];
      float4 q3 = sX4[sB3 * 8 + l];
      float4 q4 = sX4[sB4 * 8 + l];
      float4 q5 = sX4[sB5 * 8 + l];
      float4 q6 = sX4[sB6 * 8 + l];
      float4 q7 = sX4[sB7 * 8 + l];
      a0.x += q0.x; a0.y += q0.y; a0.z += q0.z; a0.w += q0.w;
      a1.x += q1.x; a1.y += q1.y; a1.z += q1.z; a1.w += q1.w;
      a2.x += q2.x; a2.y += q2.y; a2.z += q2.z; a2.w += q2.w;
      a3.x += q3.x; a3.y += q3.y; a3.z += q3.z; a3.w += q3.w;
      a0.x += q4.x; a0.y += q4.y; a0.z += q4.z; a0.w += q4.w;
      a1.x += q5.x; a1.y += q5.y; a1.z += q5.z; a1.w += q5.w;
      a2.x += q6.x; a2.y += q6.y; a2.z += q6.z; a2.w += q6.w;
      a3.x += q7.x; a3.y += q7.y; a3.z += q7.z; a3.w += q7.w;
      nslots = 16;
    }

    if (d > PRE) {                             // rare overflow (deg > 16)
      for (int e2 = PRE; e2 < d; ++e2) {
        int rl = srcext[(size_t)node * CAP + e2];
        float4 v0 = sX4[rl * 8 + l];
        a0.x += v0.x; a0.y += v0.y; a0.z += v0.z; a0.w += v0.w;
      }
    }

    float corr = (float)(nslots - dp);         // over-counted self reads
    float4 o;
    o.x = (a0.x + a1.x + a2.x + a3.x - corr * w.x) * dc;
    o.y = (a0.y + a1.y + a2.y + a3.y - corr * w.y) * dc;
    o.z = (a0.z + a1.z + a2.z + a3.z - corr * w.z) * dc;
    o.w = (a0.w + a1.w + a2.w + a3.w - corr * w.w) * dc;
    z4[(size_t)node * 32 + chunk * 8 + l] = o;

    ordc = ordn; dpc = dpn; ordn = ordn2; dpn = dpn2;
    c0 = n0; c1 = n1; c2 = n2; c3 = n3;
  }
}

// ---------------------------------------------------------------------------
// W prep: 3-way bf16 split (hi/mid/lo) packed in MFMA B-fragment order.
// ---------------------------------------------------------------------------

__global__ __launch_bounds__(256) void wsplit_kernel(
    const float* __restrict__ W0, const float* __restrict__ W1,
    const float* __restrict__ W2, ushort* __restrict__ wpk) {
  int id = blockIdx.x * 256 + threadIdx.x;     // 3*16384 total
  int L = id >> 14;
  int r = id & 16383;                          // ((kt*8+nt)*64+lane)*8+i
  int i = r & 7;
  int lane = (r >> 3) & 63;
  int nt = (r >> 9) & 7;
  int kt = (r >> 12) & 3;
  int k = kt * 32 + (lane >> 4) * 8 + i;
  int n = nt * 16 + (lane & 15);
  const float* W = (L == 0) ? W0 : (L == 1) ? W1 : W2;
  float v = W[k * HDIM + n];
  ushort h = f2bf(v);
  float r1 = v - bf2f(h);
  ushort m = f2bf(r1);
  ushort lo = f2bf(r1 - bf2f(m));
  size_t base = (size_t)L * 3 * 16384 + (size_t)r;
  wpk[base] = h;
  wpk[base + 16384] = m;
  wpk[base + 32768] = lo;
}

// ---------------------------------------------------------------------------
// conv R11: per-kt LDS-staged, double-buffered B fragments.
// R10 counters: MfmaUtil 16%, VALU 15%, occ 19% -> latency-bound. Causes:
// (a) all 4 kt A-slices split up-front (96 VGPR live) + 64 AGPR acc -> only
// 2 waves/SIMD; (b) 3 global B-loads (~250cy L2) per (kt,nt) unhidden, and
// each wave re-read the block's same 96 KB of wpk.
// Now: block stages one kt-slice (3x8KB=24KB) into a 2x24KB LDS dbuf —
// global loads issue at phase top (T14), ds_write after the phase barrier;
// MFMA phase reads conflict-free ds_read_b128 (contiguous 16B/lane). L2
// wpk traffic /4. A is split per-kt (24 VGPR live) with next-kt prefetch.
// ---------------------------------------------------------------------------

__global__ __launch_bounds__(256) void conv_mfma_kernel(
    float* __restrict__ zh, const ushort* __restrict__ wpk,
    const float* __restrict__ bias, const float* __restrict__ p,
    float* __restrict__ score) {
  __shared__ short sB[2][12288];               // 2 x 24 KB kt-slices
  int t = threadIdx.x;
  int wv = t >> 6, l = t & 63;
  int lr = l & 15, lq = l >> 4;                // A-row in tile, quarter
  int arowA = blockIdx.x * 128 + wv * 16 + lr;
  int arowB = arowA + 64;
  const float* zrowA = zh + (size_t)arowA * HDIM + lq * 8;
  const float* zrowB = zh + (size_t)arowB * HDIM + lq * 8;

  // fragment idx within staged slice: idx = (s*8+nt)*64+l, s=idx>>9.
  // wpk (this level) as int4 fragments: src = s*2048 + kt*512 + (idx&511).
  const int4* wp4 = (const int4*)wpk;
  int i0 = t, i1 = t + 256, i2 = t + 512;
  int i3 = t + 768, i4 = t + 1024, i5 = t + 1280;
  int s0 = (i0 >> 9) * 2048 + (i0 & 511);
  int s1 = (i1 >> 9) * 2048 + (i1 & 511);
  int s2 = (i2 >> 9) * 2048 + (i2 & 511);
  int s3 = (i3 >> 9) * 2048 + (i3 & 511);
  int s4 = (i4 >> 9) * 2048 + (i4 & 511);
  int s5 = (i5 >> 9) * 2048 + (i5 & 511);

  // ---- prologue: stage kt=0, load A slice kt=0 ----
  int4 rg0 = wp4[s0], rg1 = wp4[s1], rg2 = wp4[s2];
  int4 rg3 = wp4[s3], rg4 = wp4[s4], rg5 = wp4[s5];
  float4 cA0 = ((const float4*)zrowA)[0];
  float4 cA1 = ((const float4*)zrowA)[1];
  float4 cB0 = ((const float4*)zrowB)[0];
  float4 cB1 = ((const float4*)zrowB)[1];
  {
    int4* sw = (int4*)sB[0];
    sw[i0] = rg0; sw[i1] = rg1; sw[i2] = rg2;
    sw[i3] = rg3; sw[i4] = rg4; sw[i5] = rg5;
  }
  __syncthreads();

  f32x4 accA[8], accB[8];
  #pragma unroll
  for (int nt = 0; nt < 8; ++nt) { accA[nt] = (f32x4)(0.f); accB[nt] = (f32x4)(0.f); }

  for (int kt = 0; kt < 4; ++kt) {
    int cur = kt & 1;
    float4 nA0, nA1, nB0, nB1;
    if (kt < 3) {                              // issue next-stage loads (vmcnt)
      int kb = (kt + 1) * 512;
      rg0 = wp4[s0 + kb]; rg1 = wp4[s1 + kb]; rg2 = wp4[s2 + kb];
      rg3 = wp4[s3 + kb]; rg4 = wp4[s4 + kb]; rg5 = wp4[s5 + kb];
      nA0 = ((const float4*)(zrowA + (kt + 1) * 32))[0];
      nA1 = ((const float4*)(zrowA + (kt + 1) * 32))[1];
      nB0 = ((const float4*)(zrowB + (kt + 1) * 32))[0];
      nB1 = ((const float4*)(zrowB + (kt + 1) * 32))[1];
    }

    // ---- split current A slice (only this kt's fragments live) ----
    s16x8 ahA, amA, alA, ahB, amB, alB;
    float fA[8] = {cA0.x, cA0.y, cA0.z, cA0.w, cA1.x, cA1.y, cA1.z, cA1.w};
    float fB[8] = {cB0.x, cB0.y, cB0.z, cB0.w, cB1.x, cB1.y, cB1.z, cB1.w};
    #pragma unroll
    for (int i = 0; i < 8; ++i) {
      ushort h = f2bf(fA[i]);
      float r1 = fA[i] - bf2f(h);
      ushort m = f2bf(r1);
      ushort lo = f2bf(r1 - bf2f(m));
      ahA[i] = (short)h; amA[i] = (short)m; alA[i] = (short)lo;
      h = f2bf(fB[i]);
      r1 = fB[i] - bf2f(h);
      m = f2bf(r1);
      lo = f2bf(r1 - bf2f(m));
      ahB[i] = (short)h; amB[i] = (short)m; alB[i] = (short)lo;
    }

    // ---- MFMA phase: 8 nt x (3 conflict-free ds_read_b128 + 12 MFMA) ----
    const s16x8* sb = (const s16x8*)sB[cur];
    #pragma unroll
    for (int nt = 0; nt < 8; ++nt) {
      s16x8 bh = sb[nt * 64 + l];
      s16x8 bm = sb[512 + nt * 64 + l];
      s16x8 bl = sb[1024 + nt * 64 + l];
      accA[nt] = __builtin_amdgcn_mfma_f32_16x16x32_bf16(ahA, bh, accA[nt], 0, 0, 0);
      accA[nt] = __builtin_amdgcn_mfma_f32_16x16x32_bf16(ahA, bm, accA[nt], 0, 0, 0);
      accA[nt] = __builtin_amdgcn_mfma_f32_16x16x32_bf16(amA, bh, accA[nt], 0, 0, 0);
      accA[nt] = __builtin_amdgcn_mfma_f32_16x16x32_bf16(ahA, bl, accA[nt], 0, 0, 0);
      accA[nt] = __builtin_amdgcn_mfma_f32_16x16x32_bf16(alA, bh, accA[nt], 0, 0, 0);
      accA[nt] = __builtin_amdgcn_mfma_f32_16x16x32_bf16(amA, bm, accA[nt], 0, 0, 0);
      accB[nt] = __builtin_amdgcn_mfma_f32_16x16x32_bf16(ahB, bh, accB[nt], 0, 0, 0);
      accB[nt] = __builtin_amdgcn_mfma_f32_16x16x32_bf16(ahB, bm, accB[nt], 0, 0, 0);
      accB[nt] = __builtin_amdgcn_mfma_f32_16x16x32_bf16(amB, bh, accB[nt], 0, 0, 0);
      accB[nt] = __builtin_amdgcn_mfma_f32_16x16x32_bf16(ahB, bl, accB[nt], 0, 0, 0);
      accB[nt] = __builtin_amdgcn_mfma_f32_16x16x32_bf16(alB, bh, accB[nt], 0, 0, 0);
      accB[nt] = __builtin_amdgcn_mfma_f32_16x16x32_bf16(amB, bm, accB[nt], 0, 0, 0);
    }
    __syncthreads();                           // all reads of buf[cur] done
    if (kt < 3) {
      int4* sw = (int4*)sB[cur ^ 1];           // write-late (T14)
      sw[i0] = rg0; sw[i1] = rg1; sw[i2] = rg2;
      sw[i3] = rg3; sw[i4] = rg4; sw[i5] = rg5;
      cA0 = nA0; cA1 = nA1; cB0 = nB0; cB1 = nB1;
    }
    __syncthreads();                           // writes visible
  }

  // ---- epilogue: bias + relu + score + in-place store (both tiles) ----
  // C/D layout (m89-verified): row = lq*4 + j, col = nt*16 + lr
  int orowA = blockIdx.x * 128 + wv * 16 + lq * 4;
  int orowB = orowA + 64;
  float partA[4] = {0.f, 0.f, 0.f, 0.f};
  float partB[4] = {0.f, 0.f, 0.f, 0.f};
  #pragma unroll
  for (int nt = 0; nt < 8; ++nt) {
    float bv = bias[nt * 16 + lr];
    float pv = p[nt * 16 + lr];
    #pragma unroll
    for (int j = 0; j < 4; ++j) {
      float hA = fmaxf(accA[nt][j] + bv, 0.f);
      partA[j] += hA * pv;
      zh[(size_t)(orowA + j) * HDIM + nt * 16 + lr] = hA;
      float hB = fmaxf(accB[nt][j] + bv, 0.f);
      partB[j] += hB * pv;
      zh[(size_t)(orowB + j) * HDIM + nt * 16 + lr] = hB;
    }
  }
  #pragma unroll
  for (int j = 0; j < 4; ++j) {
    #pragma unroll
    for (int s = 1; s < 16; s <<= 1) {
      partA[j] += __shfl_xor(partA[j], s);
      partB[j] += __shfl_xor(partB[j], s);
    }
    if (lr == 0) {
      score[orowA + j] = partA[j];
      score[orowB + j] = partB[j];
    }
  }
}

// ---------------------------------------------------------------------------
// MEGA: per-graph block (P threads) — sort + pool/readout + relabel + next-
// layer count/fill via LDS. Tail (L<2) also emits the degree-bucketed
// order/odeg for the NEXT level's agg. (R9 structure, unchanged.)
// ---------------------------------------------------------------------------

__global__ __launch_bounds__(1024) void topk_mega_kernel(
    const float* __restrict__ score, const float* __restrict__ p,
    const float* __restrict__ h, float* __restrict__ xo,
    const int* __restrict__ in_r, const int* __restrict__ in_c,
    int* __restrict__ out_r, int* __restrict__ out_c,
    int* __restrict__ meta8, int* __restrict__ srcext,
    int* __restrict__ cnt, float* __restrict__ acc,
    int* __restrict__ order, int* __restrict__ odeg,
    float* __restrict__ outf, int P, int K, int L) {
  __shared__ float sv[1024];
  __shared__ int si[1024];
  __shared__ int snew[1024];
  __shared__ int scnt[512];
  __shared__ int bb[2];
  __shared__ float s_pn;
  __shared__ float4 smx[32][32], ssm[32][32];
  int g = blockIdx.x;
  int t = threadIdx.x;

  if (L < 2 && t < 512) scnt[t] = 0;
  if (t < 2) bb[t] = 0;
  snew[t] = -1;
  if (t < 128) { float v = p[t]; sv[t] = v * v; }
  __syncthreads();
  for (int off = 64; off; off >>= 1) {
    if (t < off) sv[t] += sv[t + off];
    __syncthreads();
  }
  if (t == 0) s_pn = sqrtf(sv[0]);
  __syncthreads();
  float pn = s_pn;

  sv[t] = score[(size_t)g * P + t];
  si[t] = t;
  for (int size = 2; size <= P; size <<= 1) {
    for (int stride = size >> 1; stride; stride >>= 1) {
      __syncthreads();
      int j = t ^ stride;
      if (j > t) {
        float a = sv[t], b = sv[j];
        int ia = si[t], ib = si[j];
        bool tFirst = (a > b) || (a == b && ia < ib);
        bool up = ((t & size) == 0);
        if (up ? !tFirst : tFirst) {
          sv[t] = b; sv[j] = a;
          si[t] = ib; si[j] = ia;
        }
      }
    }
  }
  __syncthreads();
  if (t < K) {
    snew[si[t]] = t;                           // graph-LOCAL new id
    sv[t] = tanhf(sv[t] / pn);                 // sv now holds the scale
  }
  __syncthreads();

  // ---- gather + readout: group = 32 lanes, 16 rows per group ----
  int lane = t & 31, grp = t >> 5;             // ngrp = P/32; K/ngrp == 16
  const float4* h4 = (const float4*)h;
  float4* xo4 = (float4*)xo;
  size_t hbase = (size_t)g * P * 32;
  float4 mx = make_float4(-INFINITY, -INFINITY, -INFINITY, -INFINITY);
  float4 sm = make_float4(0.f, 0.f, 0.f, 0.f);
  #pragma unroll
  for (int i = 0; i < 16; ++i) {
    int j = grp * 16 + i;
    float th = sv[j];
    float4 v = h4[hbase + (size_t)si[j] * 32 + lane];
    v.x *= th; v.y *= th; v.z *= th; v.w *= th;
    xo4[((size_t)g * K + j) * 32 + lane] = v;
    mx.x = fmaxf(mx.x, v.x); mx.y = fmaxf(mx.y, v.y);
    mx.z = fmaxf(mx.z, v.z); mx.w = fmaxf(mx.w, v.w);
    sm.x += v.x; sm.y += v.y; sm.z += v.z; sm.w += v.w;
  }
  smx[grp][lane] = mx;
  ssm[grp][lane] = sm;
  __syncthreads();
  int ngrp = P >> 5;
  if (grp == 0) {
    for (int s2 = 1; s2 < ngrp; ++s2) {
      float4 m2 = smx[s2][lane], s3 = ssm[s2][lane];
      mx.x = fmaxf(mx.x, m2.x); mx.y = fmaxf(mx.y, m2.y);
      mx.z = fmaxf(mx.z, m2.z); mx.w = fmaxf(mx.w, m2.w);
      sm.x += s3.x; sm.y += s3.y; sm.z += s3.z; sm.w += s3.w;
    }
    int c0 = lane * 4;
    if (L < 2) {
      float* amax = acc + (size_t)L * BG * 256 + (size_t)g * 256;
      float* asum = amax + 128;
      amax[c0 + 0] = mx.x; amax[c0 + 1] = mx.y;
      amax[c0 + 2] = mx.z; amax[c0 + 3] = mx.w;
      asum[c0 + 0] = sm.x; asum[c0 + 1] = sm.y;
      asum[c0 + 2] = sm.z; asum[c0 + 3] = sm.w;
    } else {                                   // stash own readout in sv
      sv[c0 + 0] = mx.x; sv[c0 + 1] = mx.y;
      sv[c0 + 2] = mx.z; sv[c0 + 3] = mx.w;
      sv[128 + c0 + 0] = sm.x; sv[128 + c0 + 1] = sm.y;
      sv[128 + c0 + 2] = sm.z; sv[128 + c0 + 3] = sm.w;
    }
  }

  if (L == 2) {                                // fold final combine in
    __syncthreads();
    float v;
    const float* a0 = acc + (size_t)g * 256;
    const float* a1 = acc + (size_t)BG * 256 + (size_t)g * 256;
    if (t < 128) {
      v = a0[t] + a1[t] + sv[t];
    } else {
      v = a0[t] * (1.f / 512.f) + a1[t] * (1.f / 256.f) + sv[t] * (1.f / 128.f);
    }
    outf[g * 256 + t] = v;
    return;
  }

  // ---- relabel + count + fill in ONE pass (single LDS atomic per edge) ----
  int ept = EPG / P;                           // 8 (P=1024) or 16 (P=512)
  int ebase = g * EPG;
  for (int i = 0; i < ept; ++i) {
    int e = ebase + i * P + t;                 // coalesced
    int r = in_r[e];
    int nr = -1, nc = -1;
    if (r >= 0) {
      nr = snew[r & (P - 1)];
      nc = snew[in_c[e] & (P - 1)];
    }
    bool ok = (nr >= 0) && (nc >= 0);
    out_r[e] = ok ? g * K + nr : -1;
    out_c[e] = ok ? g * K + nc : -1;
    if (ok) {
      int pos = atomicAdd(&scnt[nc], 1);
      size_t gnode = (size_t)g * K + nc;
      if (pos < PRE) {
        meta8[gnode * PRE + pos] = nr;
      } else if (pos < CAP) {
        srcext[gnode * CAP + pos] = nr;
      }
    }
  }
  __syncthreads();                             // scnt complete
  if (t < K) cnt[g * K + t] = scnt[t];         // deg for next agg (coalesced)

  // ---- degree-bucket order for next level's agg (lows first) ----
  int bkt = 0, bpos = 0, bdeg = 0;
  if (t < K) {
    bdeg = scnt[t];
    bkt = bdeg > 8 ? 1 : 0;
    bpos = atomicAdd(&bb[bkt], 1);
  }
  __syncthreads();
  if (t < K) {
    int slot = bkt ? bb[0] + bpos : bpos;
    order[g * K + slot] = t;
    odeg[g * K + slot] = bdeg;
  }
}

// ---------------------------------------------------------------------------
// launch
// ---------------------------------------------------------------------------

extern "C" void kernel_launch(void* const* d_in, const int* in_sizes, int n_in,
                              void* d_out, int out_size, void* d_ws, size_t ws_size,
                              hipStream_t stream) {
  const float* x0 = (const float*)d_in[0];
  const int* erow = (const int*)d_in[1];
  const int* ecol = (const int*)d_in[2];
  const float* Wm[3] = {(const float*)d_in[3], (const float*)d_in[6], (const float*)d_in[9]};
  const float* bm[3] = {(const float*)d_in[4], (const float*)d_in[7], (const float*)d_in[10]};
  const float* pm[3] = {(const float*)d_in[5], (const float*)d_in[8], (const float*)d_in[11]};

  char* w = (char*)d_ws;
  size_t off = 0;
  auto alloc = [&](size_t bytes) -> void* {
    void* ptr = w + off;
    off = (off + bytes + 255) & ~(size_t)255;
    return ptr;
  };
  int* cur_row = (int*)alloc((size_t)NEDGE * 4);
  int* cur_col = (int*)alloc((size_t)NEDGE * 4);
  int* meta8   = (int*)alloc((size_t)NMAX * PRE * 4);
  int* srcext  = (int*)alloc((size_t)NMAX * CAP * 4);
  int* cnt     = (int*)alloc((size_t)NMAX * 4);
  int* order   = (int*)alloc((size_t)NMAX * 4);
  int* odeg    = (int*)alloc((size_t)NMAX * 4);
  float* score = (float*)alloc((size_t)NMAX * 4);
  float* acc   = (float*)alloc((size_t)2 * BG * 256 * 4);
  float* zh    = (float*)alloc((size_t)NMAX * HDIM * 4);
  float* x1    = (float*)alloc((size_t)BG * 512 * HDIM * 4);
  float* x2    = (float*)alloc((size_t)BG * 256 * HDIM * 4);
  float* x3    = (float*)alloc((size_t)BG * 128 * HDIM * 4);
  ushort* wpk  = (ushort*)alloc((size_t)3 * 3 * 16384 * 2);  // packed W splits

  // allow >64 KB dynamic LDS (agg L0: 132 KB; countfill: 69.7 KB)
  hipFuncSetAttribute((const void*)agg_lds_kernel,
                      hipFuncAttributeMaxDynamicSharedMemorySize, 152 * 1024);
  hipFuncSetAttribute((const void*)countfill_lds_kernel,
                      hipFuncAttributeMaxDynamicSharedMemorySize, 72 * 1024);

  size_t cfLds = (size_t)(NPER * PRE + NPER + 2) * 4;
  countfill_lds_kernel<<<BG, 1024, cfLds, stream>>>(
      erow, ecol, cnt, meta8, srcext, order, odeg);
  wsplit_kernel<<<(3 * 16384) / 256, 256, 0, stream>>>(Wm[0], Wm[1], Wm[2], wpk);

  const float* xin = x0;
  float* xout[3] = {x1, x2, x3};
  int Ps[3] = {1024, 512, 256};

  for (int L = 0; L < 3; ++L) {
    int P = Ps[L];
    int K = P >> 1;
    int n = BG * P;
    const int* in_r = (L == 0) ? erow : cur_row;
    const int* in_c = (L == 0) ? ecol : cur_col;
    size_t ldsBytes = (size_t)(P * 33) * 4;    // 32-ch chunk + dinv

    agg_lds_kernel<<<BG * 4, 1024, ldsBytes, stream>>>(
        xin, zh, meta8, srcext, cnt, order, odeg, P);
    conv_mfma_kernel<<<n / 128, 256, 0, stream>>>(
        zh, wpk + (size_t)L * 3 * 16384, bm[L], pm[L], score);
    topk_mega_kernel<<<BG, P, 0, stream>>>(
        score, pm[L], zh, xout[L], in_r, in_c, cur_row, cur_col,
        meta8, srcext, cnt, acc, order, odeg, (float*)d_out, P, K, L);
    xin = xout[L];
  }
}

// Round 12
// 316.070 us; speedup vs baseline: 1.1928x; 1.0048x over previous
//
#include <hip/hip_runtime.h>
#include <math.h>

#define BG   128            // graphs
#define NPER 1024           // nodes per graph, level 0
#define HDIM 128            // hidden
#define NEDGE (BG * NPER * 8)
#define NMAX (BG * NPER)    // 131072
#define EPG  (NEDGE / BG)   // 8192 edges per graph (contiguous slice!)
#define CAP  48             // per-node edge capacity (Poisson(8) tail ~1e-15)
#define PRE  16             // packed-meta entries per node (P(deg>16) ~ 0.4%)

typedef __attribute__((ext_vector_type(8))) short s16x8;   // 8 bf16 (4 VGPRs)
typedef __attribute__((ext_vector_type(4))) float f32x4;   // MFMA C/D

static __device__ __forceinline__ ushort f2bf(float f) {   // RNE f32 -> bf16
  uint u = __float_as_uint(f);
  return (ushort)((u + 0x7fffu + ((u >> 16) & 1u)) >> 16);
}
static __device__ __forceinline__ float bf2f(ushort h) {
  return __uint_as_float(((uint)h) << 16);
}

extern __shared__ float ldsbuf[];

// ---------------------------------------------------------------------------
// countfill (R10 structure, R12: meta is USHORT — ids are graph-local <1024).
// LDS: smeta ushort[NPER*PRE] (32 KB) + scnt (4 KB) -> 36 KB, 4 blocks/CU.
// Flush halves to 32 KB/graph.
// ---------------------------------------------------------------------------

__global__ __launch_bounds__(1024) void countfill_lds_kernel(
    const int* __restrict__ cr, const int* __restrict__ cc,
    int* __restrict__ cnt, ushort* __restrict__ meta16,
    int* __restrict__ srcext, int* __restrict__ order,
    int* __restrict__ odeg) {
  ushort* smeta = (ushort*)ldsbuf;             // [NPER][PRE]
  int* scnt  = (int*)(smeta + NPER * PRE);     // [NPER]
  int* sbb   = scnt + NPER;                    // [2]
  int g = blockIdx.x, t = threadIdx.x;
  scnt[t] = 0;
  if (t < 2) sbb[t] = 0;
  __syncthreads();

  const int4* cr4 = (const int4*)(cr + (size_t)g * EPG);
  const int4* cc4 = (const int4*)(cc + (size_t)g * EPG);
  #pragma unroll
  for (int i = 0; i < 2; ++i) {                // 8 edges: 2x int4 per array
    int4 r = cr4[t * 2 + i];
    int4 c = cc4[t * 2 + i];
    int rl, cl, pos;
    cl = c.x & (NPER - 1); rl = r.x & (NPER - 1);
    pos = atomicAdd(&scnt[cl], 1);
    if (pos < PRE) smeta[cl * PRE + pos] = (ushort)rl;
    else if (pos < CAP) srcext[((size_t)g * NPER + cl) * CAP + pos] = rl;
    cl = c.y & (NPER - 1); rl = r.y & (NPER - 1);
    pos = atomicAdd(&scnt[cl], 1);
    if (pos < PRE) smeta[cl * PRE + pos] = (ushort)rl;
    else if (pos < CAP) srcext[((size_t)g * NPER + cl) * CAP + pos] = rl;
    cl = c.z & (NPER - 1); rl = r.z & (NPER - 1);
    pos = atomicAdd(&scnt[cl], 1);
    if (pos < PRE) smeta[cl * PRE + pos] = (ushort)rl;
    else if (pos < CAP) srcext[((size_t)g * NPER + cl) * CAP + pos] = rl;
    cl = c.w & (NPER - 1); rl = r.w & (NPER - 1);
    pos = atomicAdd(&scnt[cl], 1);
    if (pos < PRE) smeta[cl * PRE + pos] = (ushort)rl;
    else if (pos < CAP) srcext[((size_t)g * NPER + cl) * CAP + pos] = rl;
  }
  __syncthreads();

  // ---- coalesced flush: meta (32 KB) + cnt ----
  int4* mo = (int4*)(meta16 + (size_t)g * NPER * PRE);
  const int4* sm4 = (const int4*)smeta;
  #pragma unroll
  for (int i = 0; i < 2; ++i) mo[i * 1024 + t] = sm4[i * 1024 + t];
  int d = scnt[t];
  cnt[g * NPER + t] = d;

  // ---- degree-bucket order (lows first) ----
  int bkt = d > 8 ? 1 : 0;
  int bpos = atomicAdd(&sbb[bkt], 1);
  __syncthreads();
  int slot = bkt ? sbb[0] + bpos : bpos;
  order[g * NPER + slot] = t;
  odeg[g * NPER + slot] = d;
}

// ---------------------------------------------------------------------------
// Aggregation R12 = R9 structure + two fixes:
// (1) plane-padded CHANNEL-MAJOR LDS: sX4[l*(npg+2)+src]. Row-major's bank
//     index (src*32+l*4)%32 = l*4 was src-INDEPENDENT -> systematic ~8-way
//     conflict on every gather (2.3M conflict cycles measured). Now
//     (npg+2)*4 % 32 == 8 at all levels -> bank = (l*8+src*4)%32: gathers
//     spread by src (~<=2-way random), staging writes exactly 2-way (free).
// (2) ushort meta: 8 ids per int4 -> <=2 loads/node, meta FETCH halved.
// ---------------------------------------------------------------------------

__global__ __launch_bounds__(1024) void agg_lds_kernel(
    const float* __restrict__ x, float* __restrict__ z,
    const ushort* __restrict__ meta16, const int* __restrict__ srcext,
    const int* __restrict__ deg, const int* __restrict__ order,
    const int* __restrict__ odeg, int npg) {
  const int PSTR = npg + 2;                    // plane stride (float4 units)
  float4* sX4 = (float4*)ldsbuf;               // [8][PSTR] channel-major
  float* sDinv = ldsbuf + 8 * PSTR * 4;        // [npg]
  int g = blockIdx.x >> 2;
  int chunk = blockIdx.x & 3;
  int t = threadIdx.x;
  int base = g * npg;

  const float4* x4 = (const float4*)x;
  for (int i = t; i < npg * 8; i += 1024) {
    int r = i >> 3, l8 = i & 7;
    float dv = rsqrtf((float)deg[base + r] + 1.0f);
    float4 v = x4[(size_t)(base + r) * 32 + chunk * 8 + l8];
    v.x *= dv; v.y *= dv; v.z *= dv; v.w *= dv;
    sX4[l8 * PSTR + r] = v;                    // 2-way write conflict (free)
  }
  for (int i = t; i < npg; i += 1024)
    sDinv[i] = rsqrtf((float)deg[base + i] + 1.0f);

  int dl = t >> 3, l = t & 7;                  // dst-local slot, lane 0..7
  const int4* m4 = (const int4*)meta16;        // 8 ushort ids per int4
  float4* z4 = (float4*)z;

  // 2-deep pipeline: ord/odeg for slot, slot+128; meta for slot (pre-barrier)
  int ordc = order[base + dl];
  int dpc  = odeg[base + dl];
  int ordn = order[base + dl + 128];           // npg >= 256 always
  int dpn  = odeg[base + dl + 128];
  int4 c0 = m4[(size_t)(base + ordc) * 2 + 0];
  int4 c1 = {0, 0, 0, 0};
  if (dpc > 8) c1 = m4[(size_t)(base + ordc) * 2 + 1];

  __syncthreads();

  for (int slot = dl; slot < npg; slot += 128) {
    int ordn2 = ordn, dpn2 = dpn;
    if (slot + 256 < npg) {                    // prefetch order 2 ahead
      ordn2 = order[base + slot + 256];
      dpn2  = odeg[base + slot + 256];
    }
    int4 n0 = {0,0,0,0}, n1 = {0,0,0,0};
    if (slot + 128 < npg) {                    // prefetch meta 1 ahead
      n0 = m4[(size_t)(base + ordn) * 2 + 0];
      if (dpn > 8) n1 = m4[(size_t)(base + ordn) * 2 + 1];
    }

    int dst = ordc;
    int node = base + dst;
    int d = dpc > CAP ? CAP : dpc;
    int dp = d > PRE ? PRE : d;
    float dc = sDinv[dst];

    // ---- unpack 8 ids from c0 (edges 0..7) ----
    int e0 = c0.x & 0xffff, e1 = ((uint)c0.x) >> 16;
    int e2 = c0.y & 0xffff, e3 = ((uint)c0.y) >> 16;
    int e4 = c0.z & 0xffff, e5 = ((uint)c0.z) >> 16;
    int e6 = c0.w & 0xffff, e7 = ((uint)c0.w) >> 16;

    // ---- cluster A: self + edges 0..7, 9 independent ds_read_b128 ----
    int sA0 = (0 < dp) ? e0 : dst;             // invalid -> own row
    int sA1 = (1 < dp) ? e1 : dst;
    int sA2 = (2 < dp) ? e2 : dst;
    int sA3 = (3 < dp) ? e3 : dst;
    int sA4 = (4 < dp) ? e4 : dst;
    int sA5 = (5 < dp) ? e5 : dst;
    int sA6 = (6 < dp) ? e6 : dst;
    int sA7 = (7 < dp) ? e7 : dst;
    int pb = l * PSTR;                         // this lane's plane base
    float4 w  = sX4[pb + dst];                 // self row (kept for corr)
    float4 p0 = sX4[pb + sA0];
    float4 p1 = sX4[pb + sA1];
    float4 p2 = sX4[pb + sA2];
    float4 p3 = sX4[pb + sA3];
    float4 p4 = sX4[pb + sA4];
    float4 p5 = sX4[pb + sA5];
    float4 p6 = sX4[pb + sA6];
    float4 p7 = sX4[pb + sA7];
    float4 a0, a1, a2, a3;
    a0.x = w.x + p0.x; a0.y = w.y + p0.y; a0.z = w.z + p0.z; a0.w = w.w + p0.w;
    a1.x = p1.x + p5.x; a1.y = p1.y + p5.y; a1.z = p1.z + p5.z; a1.w = p1.w + p5.w;
    a2.x = p2.x + p6.x; a2.y = p2.y + p6.y; a2.z = p2.z + p6.z; a2.w = p2.w + p6.w;
    a3.x = p3.x + p7.x; a3.y = p3.y + p7.y; a3.z = p3.z + p7.z; a3.w = p3.w + p7.w;
    a0.x += p4.x; a0.y += p4.y; a0.z += p4.z; a0.w += p4.w;

    int nslots = 8;
    if (dp > 8) {                              // wave-uniform after sort
      int f0 = c1.x & 0xffff, f1 = ((uint)c1.x) >> 16;
      int f2 = c1.y & 0xffff, f3 = ((uint)c1.y) >> 16;
      int f4 = c1.z & 0xffff, f5 = ((uint)c1.z) >> 16;
      int f6 = c1.w & 0xffff, f7 = ((uint)c1.w) >> 16;
      int sB0 = (8 < dp)  ? f0 : dst;
      int sB1 = (9 < dp)  ? f1 : dst;
      int sB2 = (10 < dp) ? f2 : dst;
      int sB3 = (11 < dp) ? f3 : dst;
      int sB4 = (12 < dp) ? f4 : dst;
      int sB5 = (13 < dp) ? f5 : dst;
      int sB6 = (14 < dp) ? f6 : dst;
      int sB7 = (15 < dp) ? f7 : dst;
      float4 q0 = sX4[pb + sB0];
      float4 q1 = sX4[pb + sB1];
      float4 q2 = sX4[pb + sB2];
      float4 q3 = sX4[pb + sB3];
      float4 q4 = sX4[pb + sB4];
      float4 q5 = sX4[pb + sB5];
      float4 q6 = sX4[pb + sB6];
      float4 q7 = sX4[pb + sB7];
      a0.x += q0.x; a0.y += q0.y; a0.z += q0.z; a0.w += q0.w;
      a1.x += q1.x; a1.y += q1.y; a1.z += q1.z; a1.w += q1.w;
      a2.x += q2.x; a2.y += q2.y; a2.z += q2.z; a2.w += q2.w;
      a3.x += q3.x; a3.y += q3.y; a3.z += q3.z; a3.w += q3.w;
      a0.x += q4.x; a0.y += q4.y; a0.z += q4.z; a0.w += q4.w;
      a1.x += q5.x; a1.y += q5.y; a1.z += q5.z; a1.w += q5.w;
      a2.x += q6.x; a2.y += q6.y; a2.z += q6.z; a2.w += q6.w;
      a3.x += q7.x; a3.y += q7.y; a3.z += q7.z; a3.w += q7.w;
      nslots = 16;
    }

    if (d > PRE) {                             // rare overflow (deg > 16)
      for (int e2i = PRE; e2i < d; ++e2i) {
        int rl = srcext[(size_t)node * CAP + e2i];
        float4 v0 = sX4[pb + rl];
        a0.x += v0.x; a0.y += v0.y; a0.z += v0.z; a0.w += v0.w;
      }
    }

    float corr = (float)(nslots - dp);         // over-counted self reads
    float4 o;
    o.x = (a0.x + a1.x + a2.x + a3.x - corr * w.x) * dc;
    o.y = (a0.y + a1.y + a2.y + a3.y - corr * w.y) * dc;
    o.z = (a0.z + a1.z + a2.z + a3.z - corr * w.z) * dc;
    o.w = (a0.w + a1.w + a2.w + a3.w - corr * w.w) * dc;
    z4[(size_t)node * 32 + chunk * 8 + l] = o;

    ordc = ordn; dpc = dpn; ordn = ordn2; dpn = dpn2;
    c0 = n0; c1 = n1;
  }
}

// ---------------------------------------------------------------------------
// W prep: 3-way bf16 split (hi/mid/lo) packed in MFMA B-fragment order.
// ---------------------------------------------------------------------------

__global__ __launch_bounds__(256) void wsplit_kernel(
    const float* __restrict__ W0, const float* __restrict__ W1,
    const float* __restrict__ W2, ushort* __restrict__ wpk) {
  int id = blockIdx.x * 256 + threadIdx.x;     // 3*16384 total
  int L = id >> 14;
  int r = id & 16383;                          // ((kt*8+nt)*64+lane)*8+i
  int i = r & 7;
  int lane = (r >> 3) & 63;
  int nt = (r >> 9) & 7;
  int kt = (r >> 12) & 3;
  int k = kt * 32 + (lane >> 4) * 8 + i;
  int n = nt * 16 + (lane & 15);
  const float* W = (L == 0) ? W0 : (L == 1) ? W1 : W2;
  float v = W[k * HDIM + n];
  ushort h = f2bf(v);
  float r1 = v - bf2f(h);
  ushort m = f2bf(r1);
  ushort lo = f2bf(r1 - bf2f(m));
  size_t base = (size_t)L * 3 * 16384 + (size_t)r;
  wpk[base] = h;
  wpk[base + 16384] = m;
  wpk[base + 32768] = lo;
}

// ---------------------------------------------------------------------------
// conv R11 (unchanged): per-kt LDS-staged double-buffered B; per-kt A split.
// ---------------------------------------------------------------------------

__global__ __launch_bounds__(256) void conv_mfma_kernel(
    float* __restrict__ zh, const ushort* __restrict__ wpk,
    const float* __restrict__ bias, const float* __restrict__ p,
    float* __restrict__ score) {
  __shared__ short sB[2][12288];               // 2 x 24 KB kt-slices
  int t = threadIdx.x;
  int wv = t >> 6, l = t & 63;
  int lr = l & 15, lq = l >> 4;                // A-row in tile, quarter
  int arowA = blockIdx.x * 128 + wv * 16 + lr;
  int arowB = arowA + 64;
  const float* zrowA = zh + (size_t)arowA * HDIM + lq * 8;
  const float* zrowB = zh + (size_t)arowB * HDIM + lq * 8;

  const int4* wp4 = (const int4*)wpk;
  int i0 = t, i1 = t + 256, i2 = t + 512;
  int i3 = t + 768, i4 = t + 1024, i5 = t + 1280;
  int s0 = (i0 >> 9) * 2048 + (i0 & 511);
  int s1 = (i1 >> 9) * 2048 + (i1 & 511);
  int s2 = (i2 >> 9) * 2048 + (i2 & 511);
  int s3 = (i3 >> 9) * 2048 + (i3 & 511);
  int s4 = (i4 >> 9) * 2048 + (i4 & 511);
  int s5 = (i5 >> 9) * 2048 + (i5 & 511);

  // ---- prologue: stage kt=0, load A slice kt=0 ----
  int4 rg0 = wp4[s0], rg1 = wp4[s1], rg2 = wp4[s2];
  int4 rg3 = wp4[s3], rg4 = wp4[s4], rg5 = wp4[s5];
  float4 cA0 = ((const float4*)zrowA)[0];
  float4 cA1 = ((const float4*)zrowA)[1];
  float4 cB0 = ((const float4*)zrowB)[0];
  float4 cB1 = ((const float4*)zrowB)[1];
  {
    int4* sw = (int4*)sB[0];
    sw[i0] = rg0; sw[i1] = rg1; sw[i2] = rg2;
    sw[i3] = rg3; sw[i4] = rg4; sw[i5] = rg5;
  }
  __syncthreads();

  f32x4 accA[8], accB[8];
  #pragma unroll
  for (int nt = 0; nt < 8; ++nt) { accA[nt] = (f32x4)(0.f); accB[nt] = (f32x4)(0.f); }

  for (int kt = 0; kt < 4; ++kt) {
    int cur = kt & 1;
    float4 nA0, nA1, nB0, nB1;
    if (kt < 3) {                              // issue next-stage loads (vmcnt)
      int kb = (kt + 1) * 512;
      rg0 = wp4[s0 + kb]; rg1 = wp4[s1 + kb]; rg2 = wp4[s2 + kb];
      rg3 = wp4[s3 + kb]; rg4 = wp4[s4 + kb]; rg5 = wp4[s5 + kb];
      nA0 = ((const float4*)(zrowA + (kt + 1) * 32))[0];
      nA1 = ((const float4*)(zrowA + (kt + 1) * 32))[1];
      nB0 = ((const float4*)(zrowB + (kt + 1) * 32))[0];
      nB1 = ((const float4*)(zrowB + (kt + 1) * 32))[1];
    }

    // ---- split current A slice (only this kt's fragments live) ----
    s16x8 ahA, amA, alA, ahB, amB, alB;
    float fA[8] = {cA0.x, cA0.y, cA0.z, cA0.w, cA1.x, cA1.y, cA1.z, cA1.w};
    float fB[8] = {cB0.x, cB0.y, cB0.z, cB0.w, cB1.x, cB1.y, cB1.z, cB1.w};
    #pragma unroll
    for (int i = 0; i < 8; ++i) {
      ushort h = f2bf(fA[i]);
      float r1 = fA[i] - bf2f(h);
      ushort m = f2bf(r1);
      ushort lo = f2bf(r1 - bf2f(m));
      ahA[i] = (short)h; amA[i] = (short)m; alA[i] = (short)lo;
      h = f2bf(fB[i]);
      r1 = fB[i] - bf2f(h);
      m = f2bf(r1);
      lo = f2bf(r1 - bf2f(m));
      ahB[i] = (short)h; amB[i] = (short)m; alB[i] = (short)lo;
    }

    // ---- MFMA phase: 8 nt x (3 conflict-free ds_read_b128 + 12 MFMA) ----
    const s16x8* sb = (const s16x8*)sB[cur];
    #pragma unroll
    for (int nt = 0; nt < 8; ++nt) {
      s16x8 bh = sb[nt * 64 + l];
      s16x8 bm = sb[512 + nt * 64 + l];
      s16x8 bl = sb[1024 + nt * 64 + l];
      accA[nt] = __builtin_amdgcn_mfma_f32_16x16x32_bf16(ahA, bh, accA[nt], 0, 0, 0);
      accA[nt] = __builtin_amdgcn_mfma_f32_16x16x32_bf16(ahA, bm, accA[nt], 0, 0, 0);
      accA[nt] = __builtin_amdgcn_mfma_f32_16x16x32_bf16(amA, bh, accA[nt], 0, 0, 0);
      accA[nt] = __builtin_amdgcn_mfma_f32_16x16x32_bf16(ahA, bl, accA[nt], 0, 0, 0);
      accA[nt] = __builtin_amdgcn_mfma_f32_16x16x32_bf16(alA, bh, accA[nt], 0, 0, 0);
      accA[nt] = __builtin_amdgcn_mfma_f32_16x16x32_bf16(amA, bm, accA[nt], 0, 0, 0);
      accB[nt] = __builtin_amdgcn_mfma_f32_16x16x32_bf16(ahB, bh, accB[nt], 0, 0, 0);
      accB[nt] = __builtin_amdgcn_mfma_f32_16x16x32_bf16(ahB, bm, accB[nt], 0, 0, 0);
      accB[nt] = __builtin_amdgcn_mfma_f32_16x16x32_bf16(amB, bh, accB[nt], 0, 0, 0);
      accB[nt] = __builtin_amdgcn_mfma_f32_16x16x32_bf16(ahB, bl, accB[nt], 0, 0, 0);
      accB[nt] = __builtin_amdgcn_mfma_f32_16x16x32_bf16(alB, bh, accB[nt], 0, 0, 0);
      accB[nt] = __builtin_amdgcn_mfma_f32_16x16x32_bf16(amB, bm, accB[nt], 0, 0, 0);
    }
    __syncthreads();                           // all reads of buf[cur] done
    if (kt < 3) {
      int4* sw = (int4*)sB[cur ^ 1];           // write-late (T14)
      sw[i0] = rg0; sw[i1] = rg1; sw[i2] = rg2;
      sw[i3] = rg3; sw[i4] = rg4; sw[i5] = rg5;
      cA0 = nA0; cA1 = nA1; cB0 = nB0; cB1 = nB1;
    }
    __syncthreads();                           // writes visible
  }

  // ---- epilogue: bias + relu + score + in-place store (both tiles) ----
  // C/D layout (m89-verified): row = lq*4 + j, col = nt*16 + lr
  int orowA = blockIdx.x * 128 + wv * 16 + lq * 4;
  int orowB = orowA + 64;
  float partA[4] = {0.f, 0.f, 0.f, 0.f};
  float partB[4] = {0.f, 0.f, 0.f, 0.f};
  #pragma unroll
  for (int nt = 0; nt < 8; ++nt) {
    float bv = bias[nt * 16 + lr];
    float pv = p[nt * 16 + lr];
    #pragma unroll
    for (int j = 0; j < 4; ++j) {
      float hA = fmaxf(accA[nt][j] + bv, 0.f);
      partA[j] += hA * pv;
      zh[(size_t)(orowA + j) * HDIM + nt * 16 + lr] = hA;
      float hB = fmaxf(accB[nt][j] + bv, 0.f);
      partB[j] += hB * pv;
      zh[(size_t)(orowB + j) * HDIM + nt * 16 + lr] = hB;
    }
  }
  #pragma unroll
  for (int j = 0; j < 4; ++j) {
    #pragma unroll
    for (int s = 1; s < 16; s <<= 1) {
      partA[j] += __shfl_xor(partA[j], s);
      partB[j] += __shfl_xor(partB[j], s);
    }
    if (lr == 0) {
      score[orowA + j] = partA[j];
      score[orowB + j] = partB[j];
    }
  }
}

// ---------------------------------------------------------------------------
// MEGA (R9 structure; R12: meta scatter writes are ushort).
// ---------------------------------------------------------------------------

__global__ __launch_bounds__(1024) void topk_mega_kernel(
    const float* __restrict__ score, const float* __restrict__ p,
    const float* __restrict__ h, float* __restrict__ xo,
    const int* __restrict__ in_r, const int* __restrict__ in_c,
    int* __restrict__ out_r, int* __restrict__ out_c,
    ushort* __restrict__ meta16, int* __restrict__ srcext,
    int* __restrict__ cnt, float* __restrict__ acc,
    int* __restrict__ order, int* __restrict__ odeg,
    float* __restrict__ outf, int P, int K, int L) {
  __shared__ float sv[1024];
  __shared__ int si[1024];
  __shared__ int snew[1024];
  __shared__ int scnt[512];
  __shared__ int bb[2];
  __shared__ float s_pn;
  __shared__ float4 smx[32][32], ssm[32][32];
  int g = blockIdx.x;
  int t = threadIdx.x;

  if (L < 2 && t < 512) scnt[t] = 0;
  if (t < 2) bb[t] = 0;
  snew[t] = -1;
  if (t < 128) { float v = p[t]; sv[t] = v * v; }
  __syncthreads();
  for (int off = 64; off; off >>= 1) {
    if (t < off) sv[t] += sv[t + off];
    __syncthreads();
  }
  if (t == 0) s_pn = sqrtf(sv[0]);
  __syncthreads();
  float pn = s_pn;

  sv[t] = score[(size_t)g * P + t];
  si[t] = t;
  for (int size = 2; size <= P; size <<= 1) {
    for (int stride = size >> 1; stride; stride >>= 1) {
      __syncthreads();
      int j = t ^ stride;
      if (j > t) {
        float a = sv[t], b = sv[j];
        int ia = si[t], ib = si[j];
        bool tFirst = (a > b) || (a == b && ia < ib);
        bool up = ((t & size) == 0);
        if (up ? !tFirst : tFirst) {
          sv[t] = b; sv[j] = a;
          si[t] = ib; si[j] = ia;
        }
      }
    }
  }
  __syncthreads();
  if (t < K) {
    snew[si[t]] = t;                           // graph-LOCAL new id
    sv[t] = tanhf(sv[t] / pn);                 // sv now holds the scale
  }
  __syncthreads();

  // ---- gather + readout: group = 32 lanes, 16 rows per group ----
  int lane = t & 31, grp = t >> 5;             // ngrp = P/32; K/ngrp == 16
  const float4* h4 = (const float4*)h;
  float4* xo4 = (float4*)xo;
  size_t hbase = (size_t)g * P * 32;
  float4 mx = make_float4(-INFINITY, -INFINITY, -INFINITY, -INFINITY);
  float4 sm = make_float4(0.f, 0.f, 0.f, 0.f);
  #pragma unroll
  for (int i = 0; i < 16; ++i) {
    int j = grp * 16 + i;
    float th = sv[j];
    float4 v = h4[hbase + (size_t)si[j] * 32 + lane];
    v.x *= th; v.y *= th; v.z *= th; v.w *= th;
    xo4[((size_t)g * K + j) * 32 + lane] = v;
    mx.x = fmaxf(mx.x, v.x); mx.y = fmaxf(mx.y, v.y);
    mx.z = fmaxf(mx.z, v.z); mx.w = fmaxf(mx.w, v.w);
    sm.x += v.x; sm.y += v.y; sm.z += v.z; sm.w += v.w;
  }
  smx[grp][lane] = mx;
  ssm[grp][lane] = sm;
  __syncthreads();
  int ngrp = P >> 5;
  if (grp == 0) {
    for (int s2 = 1; s2 < ngrp; ++s2) {
      float4 m2 = smx[s2][lane], s3 = ssm[s2][lane];
      mx.x = fmaxf(mx.x, m2.x); mx.y = fmaxf(mx.y, m2.y);
      mx.z = fmaxf(mx.z, m2.z); mx.w = fmaxf(mx.w, m2.w);
      sm.x += s3.x; sm.y += s3.y; sm.z += s3.z; sm.w += s3.w;
    }
    int c0 = lane * 4;
    if (L < 2) {
      float* amax = acc + (size_t)L * BG * 256 + (size_t)g * 256;
      float* asum = amax + 128;
      amax[c0 + 0] = mx.x; amax[c0 + 1] = mx.y;
      amax[c0 + 2] = mx.z; amax[c0 + 3] = mx.w;
      asum[c0 + 0] = sm.x; asum[c0 + 1] = sm.y;
      asum[c0 + 2] = sm.z; asum[c0 + 3] = sm.w;
    } else {                                   // stash own readout in sv
      sv[c0 + 0] = mx.x; sv[c0 + 1] = mx.y;
      sv[c0 + 2] = mx.z; sv[c0 + 3] = mx.w;
      sv[128 + c0 + 0] = sm.x; sv[128 + c0 + 1] = sm.y;
      sv[128 + c0 + 2] = sm.z; sv[128 + c0 + 3] = sm.w;
    }
  }

  if (L == 2) {                                // fold final combine in
    __syncthreads();
    float v;
    const float* a0 = acc + (size_t)g * 256;
    const float* a1 = acc + (size_t)BG * 256 + (size_t)g * 256;
    if (t < 128) {
      v = a0[t] + a1[t] + sv[t];
    } else {
      v = a0[t] * (1.f / 512.f) + a1[t] * (1.f / 256.f) + sv[t] * (1.f / 128.f);
    }
    outf[g * 256 + t] = v;
    return;
  }

  // ---- relabel + count + fill in ONE pass (single LDS atomic per edge) ----
  int ept = EPG / P;                           // 8 (P=1024) or 16 (P=512)
  int ebase = g * EPG;
  for (int i = 0; i < ept; ++i) {
    int e = ebase + i * P + t;                 // coalesced
    int r = in_r[e];
    int nr = -1, nc = -1;
    if (r >= 0) {
      nr = snew[r & (P - 1)];
      nc = snew[in_c[e] & (P - 1)];
    }
    bool ok = (nr >= 0) && (nc >= 0);
    out_r[e] = ok ? g * K + nr : -1;
    out_c[e] = ok ? g * K + nc : -1;
    if (ok) {
      int pos = atomicAdd(&scnt[nc], 1);
      size_t gnode = (size_t)g * K + nc;
      if (pos < PRE) {
        meta16[gnode * PRE + pos] = (ushort)nr;
      } else if (pos < CAP) {
        srcext[gnode * CAP + pos] = nr;
      }
    }
  }
  __syncthreads();                             // scnt complete
  if (t < K) cnt[g * K + t] = scnt[t];         // deg for next agg (coalesced)

  // ---- degree-bucket order for next level's agg (lows first) ----
  int bkt = 0, bpos = 0, bdeg = 0;
  if (t < K) {
    bdeg = scnt[t];
    bkt = bdeg > 8 ? 1 : 0;
    bpos = atomicAdd(&bb[bkt], 1);
  }
  __syncthreads();
  if (t < K) {
    int slot = bkt ? bb[0] + bpos : bpos;
    order[g * K + slot] = t;
    odeg[g * K + slot] = bdeg;
  }
}

// ---------------------------------------------------------------------------
// launch
// ---------------------------------------------------------------------------

extern "C" void kernel_launch(void* const* d_in, const int* in_sizes, int n_in,
                              void* d_out, int out_size, void* d_ws, size_t ws_size,
                              hipStream_t stream) {
  const float* x0 = (const float*)d_in[0];
  const int* erow = (const int*)d_in[1];
  const int* ecol = (const int*)d_in[2];
  const float* Wm[3] = {(const float*)d_in[3], (const float*)d_in[6], (const float*)d_in[9]};
  const float* bm[3] = {(const float*)d_in[4], (const float*)d_in[7], (const float*)d_in[10]};
  const float* pm[3] = {(const float*)d_in[5], (const float*)d_in[8], (const float*)d_in[11]};

  char* w = (char*)d_ws;
  size_t off = 0;
  auto alloc = [&](size_t bytes) -> void* {
    void* ptr = w + off;
    off = (off + bytes + 255) & ~(size_t)255;
    return ptr;
  };
  int* cur_row = (int*)alloc((size_t)NEDGE * 4);
  int* cur_col = (int*)alloc((size_t)NEDGE * 4);
  ushort* meta16 = (ushort*)alloc((size_t)NMAX * PRE * 2);
  int* srcext  = (int*)alloc((size_t)NMAX * CAP * 4);
  int* cnt     = (int*)alloc((size_t)NMAX * 4);
  int* order   = (int*)alloc((size_t)NMAX * 4);
  int* odeg    = (int*)alloc((size_t)NMAX * 4);
  float* score = (float*)alloc((size_t)NMAX * 4);
  float* acc   = (float*)alloc((size_t)2 * BG * 256 * 4);
  float* zh    = (float*)alloc((size_t)NMAX * HDIM * 4);
  float* x1    = (float*)alloc((size_t)BG * 512 * HDIM * 4);
  float* x2    = (float*)alloc((size_t)BG * 256 * HDIM * 4);
  float* x3    = (float*)alloc((size_t)BG * 128 * HDIM * 4);
  ushort* wpk  = (ushort*)alloc((size_t)3 * 3 * 16384 * 2);  // packed W splits

  // allow >64 KB dynamic LDS (agg L0: 135.5 KB)
  hipFuncSetAttribute((const void*)agg_lds_kernel,
                      hipFuncAttributeMaxDynamicSharedMemorySize, 152 * 1024);

  size_t cfLds = (size_t)(NPER * PRE * 2 + NPER * 4 + 8);
  countfill_lds_kernel<<<BG, 1024, cfLds, stream>>>(
      erow, ecol, cnt, meta16, srcext, order, odeg);
  wsplit_kernel<<<(3 * 16384) / 256, 256, 0, stream>>>(Wm[0], Wm[1], Wm[2], wpk);

  const float* xin = x0;
  float* xout[3] = {x1, x2, x3};
  int Ps[3] = {1024, 512, 256};

  for (int L = 0; L < 3; ++L) {
    int P = Ps[L];
    int K = P >> 1;
    int n = BG * P;
    const int* in_r = (L == 0) ? erow : cur_row;
    const int* in_c = (L == 0) ? ecol : cur_col;
    size_t ldsBytes = (size_t)(8 * (P + 2) * 16 + P * 4);  // planes + dinv

    agg_lds_kernel<<<BG * 4, 1024, ldsBytes, stream>>>(
        xin, zh, meta16, srcext, cnt, order, odeg, P);
    conv_mfma_kernel<<<n / 128, 256, 0, stream>>>(
        zh, wpk + (size_t)L * 3 * 16384, bm[L], pm[L], score);
    topk_mega_kernel<<<BG, P, 0, stream>>>(
        score, pm[L], zh, xout[L], in_r, in_c, cur_row, cur_col,
        meta16, srcext, cnt, acc, order, odeg, (float*)d_out, P, K, L);
    xin = xout[L];
  }
}